// Round 1
// baseline (673.957 us; speedup 1.0000x reference)
//
#include <hip/hip_runtime.h>
#include <math.h>

#define NB 8   // nodes per wave-tile in k_linear

__device__ __forceinline__ float wred_sum(float x) {
#pragma unroll
  for (int off = 32; off > 0; off >>= 1) x += __shfl_xor(x, off, 64);
  return x;
}

// Exact float atomic max via sign-split (monotone under both ops, any interleaving)
__device__ __forceinline__ void atomicMaxF(float* addr, float val) {
  int iv = __float_as_int(val);
  if (iv >= 0) {
    atomicMax((int*)addr, iv);
  } else {
    atomicMin((unsigned int*)addr, __float_as_uint(val));
  }
}

__global__ void k_init(float* __restrict__ smax, int* __restrict__ deg,
                       int* __restrict__ cursor, int n) {
  int i = blockIdx.x * blockDim.x + threadIdx.x;
  if (i < n) {
    smax[i] = __int_as_float(0xff800000);  // -inf
    deg[i] = 0;
    cursor[i] = 0;
  }
}

// q = norm(x_S@Wq^T); k = norm(x_H@Wk^T); v = norm(x_H@Wv^T)
// a[n] = Ws[0:64].q[n]; b[n] = Ws[64:128].k[n]; v stored.
__global__ __launch_bounds__(256) void k_linear(
    const float* __restrict__ xH, const float* __restrict__ xS,
    const float* __restrict__ Wq, const float* __restrict__ Wk,
    const float* __restrict__ Wv, const float* __restrict__ Ws,
    float* __restrict__ a, float* __restrict__ b, float* __restrict__ v,
    int n_nodes, int n_waves) {
  int wid = (blockIdx.x * blockDim.x + threadIdx.x) >> 6;
  int lane = threadIdx.x & 63;
  if (wid >= n_waves) return;
  int tile = wid / 3, m = wid % 3;
  int n0 = tile * NB;

  const float* X = (m == 0) ? xS : xH;
  const float* W = (m == 0) ? Wq : (m == 1) ? Wk : Wv;
  const float4* wrow = (const float4*)(W + (size_t)lane * 128);

  float acc[NB];
#pragma unroll
  for (int t = 0; t < NB; ++t) acc[t] = 0.f;

#pragma unroll 4
  for (int d4 = 0; d4 < 32; ++d4) {
    float4 w4 = wrow[d4];
#pragma unroll
    for (int t = 0; t < NB; ++t) {
      int nn = n0 + t; if (nn >= n_nodes) nn = n_nodes - 1;
      float4 x4 = *(const float4*)(X + (size_t)nn * 128 + d4 * 4);
      acc[t] = fmaf(x4.x, w4.x, acc[t]);
      acc[t] = fmaf(x4.y, w4.y, acc[t]);
      acc[t] = fmaf(x4.z, w4.z, acc[t]);
      acc[t] = fmaf(x4.w, w4.w, acc[t]);
    }
  }

  float wsv = (m == 0) ? Ws[lane] : (m == 1) ? Ws[64 + lane] : 0.f;

#pragma unroll
  for (int t = 0; t < NB; ++t) {
    int n = n0 + t;
    if (n >= n_nodes) break;           // uniform across wave
    float q = acc[t];
    float s2 = wred_sum(q * q);
    float q0 = __shfl(q, 0, 64);
    float inner = s2 - 2.f * q0 * q0;  // Lorentz inner
    float dn = sqrtf(fmaxf(fabsf(inner), 1e-8f));
    float val = q / dn;
    if (m == 2) {
      v[(size_t)n * 64 + lane] = val;
    } else {
      float r = wred_sum(val * wsv);
      if (lane == 0) (m == 0 ? a : b)[n] = r;
    }
  }
}

__global__ void k_edge_score(const int* __restrict__ ei, const float* __restrict__ a,
                             const float* __restrict__ b, float* __restrict__ score,
                             float* __restrict__ smax, int* __restrict__ deg, int n_edges) {
  int e = blockIdx.x * blockDim.x + threadIdx.x;
  if (e >= n_edges) return;
  int src = ei[e];
  int dst = ei[n_edges + e];
  float s = a[src] + b[dst];
  float sc = s > 0.f ? s : 0.01f * s;   // LeakyReLU(0.01)
  score[e] = sc;
  atomicMaxF(smax + src, sc);
  atomicAdd(deg + src, 1);
}

__global__ __launch_bounds__(1024) void k_scan(const int* __restrict__ deg,
                                               int* __restrict__ rowptr, int n) {
  const int T = 1024;
  __shared__ int s[T];
  int tid = threadIdx.x;
  int chunk = (n + T - 1) / T;
  int start = tid * chunk;
  int end = start + chunk; if (end > n) end = n; if (start > n) start = n;
  int sum = 0;
  for (int i = start; i < end; ++i) sum += deg[i];
  s[tid] = sum;
  __syncthreads();
  for (int off = 1; off < T; off <<= 1) {
    int t = (tid >= off) ? s[tid - off] : 0;
    __syncthreads();
    s[tid] += t;
    __syncthreads();
  }
  int run = s[tid] - sum;  // exclusive prefix
  for (int i = start; i < end; ++i) { rowptr[i] = run; run += deg[i]; }
  if (tid == T - 1) rowptr[n] = s[T - 1];
}

__global__ void k_csr(const int* __restrict__ ei, const float* __restrict__ score,
                      const int* __restrict__ rowptr, int* __restrict__ cursor,
                      int* __restrict__ csr_dst, float* __restrict__ csr_score, int n_edges) {
  int e = blockIdx.x * blockDim.x + threadIdx.x;
  if (e >= n_edges) return;
  int src = ei[e];
  int slot = atomicAdd(cursor + src, 1);
  int idx = rowptr[src] + slot;
  csr_dst[idx] = ei[n_edges + e];
  csr_score[idx] = score[e];
}

// Per node: softmax-weighted agg of v[dst], origin+normalize, project (normalize),
// add x_H, normalize, write out.
__global__ __launch_bounds__(256) void k_agg(
    const int* __restrict__ rowptr, const int* __restrict__ csr_dst,
    const float* __restrict__ csr_score, const float* __restrict__ smax,
    const float* __restrict__ v, const float* __restrict__ Wproj,
    const float* __restrict__ xH, float* __restrict__ out, int n_nodes) {
  __shared__ float om_s[4][64];
  int wib = threadIdx.x >> 6;
  int lane = threadIdx.x & 63;
  int n = blockIdx.x * 4 + wib;
  bool valid = (n < n_nodes);

  int r0 = 0, r1 = 0;
  if (valid) { r0 = rowptr[n]; r1 = rowptr[n + 1]; }
  float agg = 0.f, ssum = 0.f;
  float mx = (valid && r1 > r0) ? smax[n] : 0.f;
  for (int i = r0; i < r1; ++i) {
    int d = csr_dst[i];           // wave-uniform broadcast
    float w = __expf(csr_score[i] - mx);
    ssum += w;
    agg = fmaf(w, v[(size_t)d * 64 + lane], agg);
  }
  if (r1 > r0) agg /= ssum;

  // out = to_manifold(origin + agg)
  float ov = agg + (lane == 0 ? 1.0f : 0.f);
  float s2 = wred_sum(ov * ov);
  float o0 = __shfl(ov, 0, 64);
  float inner = s2 - 2.f * o0 * o0;
  float dn = sqrtf(fmaxf(fabsf(inner), 1e-8f));
  if (valid) om_s[wib][lane] = ov / dn;
  __syncthreads();

  if (!valid) return;

  // x = to_manifold(om @ Wproj^T)  (128-dim: lane -> dims {lane, lane+64})
  float p0 = 0.f, p1 = 0.f;
  const float4* om4 = (const float4*)om_s[wib];
  const float4* wpa = (const float4*)(Wproj + (size_t)lane * 64);
  const float4* wpb = (const float4*)(Wproj + (size_t)(lane + 64) * 64);
#pragma unroll
  for (int t4 = 0; t4 < 16; ++t4) {
    float4 o4 = om4[t4];
    float4 wa = wpa[t4];
    float4 wb = wpb[t4];
    p0 += o4.x * wa.x + o4.y * wa.y + o4.z * wa.z + o4.w * wa.w;
    p1 += o4.x * wb.x + o4.y * wb.y + o4.z * wb.z + o4.w * wb.w;
  }
  float s2p = wred_sum(p0 * p0 + p1 * p1);
  float p00 = __shfl(p0, 0, 64);
  float innerp = s2p - 2.f * p00 * p00;
  float dnp = sqrtf(fmaxf(fabsf(innerp), 1e-8f));
  float x0 = p0 / dnp;
  float x1 = p1 / dnp;

  // z = to_manifold(x + x_H)
  float z0 = x0 + xH[(size_t)n * 128 + lane];
  float z1 = x1 + xH[(size_t)n * 128 + 64 + lane];
  float s2z = wred_sum(z0 * z0 + z1 * z1);
  float zz0 = __shfl(z0, 0, 64);
  float innerz = s2z - 2.f * zz0 * zz0;
  float dnz = sqrtf(fmaxf(fabsf(innerz), 1e-8f));
  out[(size_t)n * 128 + lane] = z0 / dnz;
  out[(size_t)n * 128 + 64 + lane] = z1 / dnz;
}

extern "C" void kernel_launch(void* const* d_in, const int* in_sizes, int n_in,
                              void* d_out, int out_size, void* d_ws, size_t ws_size,
                              hipStream_t stream) {
  const float* xH    = (const float*)d_in[0];
  const float* xS    = (const float*)d_in[1];
  const int*   ei    = (const int*)d_in[2];
  const float* Wq    = (const float*)d_in[3];
  const float* Wk    = (const float*)d_in[4];
  const float* Wv    = (const float*)d_in[5];
  const float* Ws    = (const float*)d_in[6];
  const float* Wproj = (const float*)d_in[7];
  float* out = (float*)d_out;

  int N = in_sizes[0] / 128;
  int E = in_sizes[2] / 2;

  char* ws = (char*)d_ws;
  size_t off = 0;
  auto alloc = [&](size_t bytes) {
    void* p = ws + off;
    off = (off + bytes + 255) & ~(size_t)255;
    return p;
  };
  float* a         = (float*)alloc((size_t)N * 4);
  float* b         = (float*)alloc((size_t)N * 4);
  float* smax      = (float*)alloc((size_t)N * 4);
  float* v         = (float*)alloc((size_t)N * 64 * 4);
  float* score     = (float*)alloc((size_t)E * 4);
  float* csr_score = (float*)alloc((size_t)E * 4);
  int* deg         = (int*)alloc((size_t)N * 4);
  int* cursor      = (int*)alloc((size_t)N * 4);
  int* rowptr      = (int*)alloc((size_t)(N + 1) * 4);
  int* csr_dst     = (int*)alloc((size_t)E * 4);

  k_init<<<(N + 255) / 256, 256, 0, stream>>>(smax, deg, cursor, N);

  int n_waves = ((N + NB - 1) / NB) * 3;
  k_linear<<<(n_waves + 3) / 4, 256, 0, stream>>>(xH, xS, Wq, Wk, Wv, Ws, a, b, v, N, n_waves);

  k_edge_score<<<(E + 255) / 256, 256, 0, stream>>>(ei, a, b, score, smax, deg, E);

  k_scan<<<1, 1024, 0, stream>>>(deg, rowptr, N);

  k_csr<<<(E + 255) / 256, 256, 0, stream>>>(ei, score, rowptr, cursor, csr_dst, csr_score, E);

  k_agg<<<(N + 3) / 4, 256, 0, stream>>>(rowptr, csr_dst, csr_score, smax, v, Wproj, xH, out, N);
}

// Round 2
// 497.998 us; speedup vs baseline: 1.3533x; 1.3533x over previous
//
#include <hip/hip_runtime.h>
#include <math.h>

struct __align__(8) EdgeRec { int d; float s; };

__global__ void k_init(int* __restrict__ deg, int* __restrict__ cursor, int n) {
  int i = blockIdx.x * blockDim.x + threadIdx.x;
  if (i < n) { deg[i] = 0; cursor[i] = 0; }
}

// Transposed linear: lane = node. acc[64] per lane; W via uniform (scalar) loads.
// m=0: a[n] = Ws[0:64] . norm(xS@Wq^T)
// m=1: b[n] = Ws[64:128] . norm(xH@Wk^T)
// m=2: v[n] = norm(xH@Wv^T)
__global__ __launch_bounds__(256, 2) void k_linear(
    const float* __restrict__ xH, const float* __restrict__ xS,
    const float* __restrict__ Wq, const float* __restrict__ Wk,
    const float* __restrict__ Wv, const float* __restrict__ Ws,
    float* __restrict__ a, float* __restrict__ b, float* __restrict__ v,
    int n_nodes, int n_tiles) {
  int wid = __builtin_amdgcn_readfirstlane((blockIdx.x * blockDim.x + threadIdx.x) >> 6);
  if (wid >= 3 * n_tiles) return;
  int lane = threadIdx.x & 63;
  int m = wid / n_tiles;           // uniform: same-m waves adjacent -> K$ sharing
  int tile = wid - m * n_tiles;
  int n = tile * 64 + lane;
  if (n >= n_nodes) n = n_nodes - 1;  // clamped dups write identical values

  const float* X = (m == 0) ? xS : xH;
  const float* W = (m == 0) ? Wq : (m == 1) ? Wk : Wv;
  const float* xrow = X + (size_t)n * 128;

  float acc[64];
#pragma unroll
  for (int d = 0; d < 64; ++d) acc[d] = 0.f;

  for (int c = 0; c < 4; ++c) {       // j-chunks of 32
    float xr[32];
    const float4* xp = (const float4*)(xrow + c * 32);
#pragma unroll
    for (int q4 = 0; q4 < 8; ++q4) {
      float4 t = xp[q4];
      xr[4 * q4 + 0] = t.x; xr[4 * q4 + 1] = t.y;
      xr[4 * q4 + 2] = t.z; xr[4 * q4 + 3] = t.w;
    }
    const float* wbase = W + c * 32;  // uniform -> s_load with imm offsets
#pragma unroll
    for (int d = 0; d < 64; ++d) {
#pragma unroll
      for (int jj = 0; jj < 32; ++jj)
        acc[d] = fmaf(wbase[d * 128 + jj], xr[jj], acc[d]);
    }
  }

  float s2 = 0.f;
#pragma unroll
  for (int d = 0; d < 64; ++d) s2 = fmaf(acc[d], acc[d], s2);
  float inner = s2 - 2.f * acc[0] * acc[0];          // Lorentz inner
  float inv = 1.f / sqrtf(fmaxf(fabsf(inner), 1e-8f));

  if (m == 2) {
    float4* vp = (float4*)(v + (size_t)n * 64);
#pragma unroll
    for (int d4 = 0; d4 < 16; ++d4)
      vp[d4] = make_float4(acc[4 * d4] * inv, acc[4 * d4 + 1] * inv,
                           acc[4 * d4 + 2] * inv, acc[4 * d4 + 3] * inv);
  } else {
    const float* wsrow = Ws + (m == 1 ? 64 : 0);     // uniform -> s_load
    float r = 0.f;
#pragma unroll
    for (int d = 0; d < 64; ++d) r = fmaf(acc[d], wsrow[d], r);
    (m == 0 ? a : b)[n] = r * inv;
  }
}

__global__ void k_deg(const int* __restrict__ ei, int* __restrict__ deg, int n_edges) {
  int e = blockIdx.x * blockDim.x + threadIdx.x;
  if (e < n_edges) atomicAdd(deg + ei[e], 1);
}

// ---- 3-phase block scan: deg -> rowptr (exclusive) ----
__global__ __launch_bounds__(1024) void k_scan1(const int* __restrict__ deg,
                                                int* __restrict__ bsum, int n) {
  __shared__ int ws[16];
  int i = blockIdx.x * 1024 + threadIdx.x;
  int x = (i < n) ? deg[i] : 0;
  int s = x;
#pragma unroll
  for (int off = 1; off < 64; off <<= 1) s += __shfl_xor(s, off, 64);
  if ((threadIdx.x & 63) == 0) ws[threadIdx.x >> 6] = s;
  __syncthreads();
  if (threadIdx.x == 0) {
    int t = 0;
#pragma unroll
    for (int k = 0; k < 16; ++k) t += ws[k];
    bsum[blockIdx.x] = t;
  }
}

__global__ void k_scan2(int* __restrict__ bsum, int nb) {  // 1 wave, nb<=64
  int lane = threadIdx.x;
  int orig = (lane < nb) ? bsum[lane] : 0;
  int x = orig;
#pragma unroll
  for (int off = 1; off < 64; off <<= 1) {
    int y = __shfl_up(x, off, 64);
    if (lane >= off) x += y;
  }
  if (lane < nb) bsum[lane] = x - orig;  // exclusive
}

__global__ __launch_bounds__(1024) void k_scan3(const int* __restrict__ deg,
                                                const int* __restrict__ bsum,
                                                int* __restrict__ rowptr, int n) {
  __shared__ int ws[16];
  __shared__ int woff[16];
  int i = blockIdx.x * 1024 + threadIdx.x;
  int lane = threadIdx.x & 63, w = threadIdx.x >> 6;
  int x = (i < n) ? deg[i] : 0;
  int inc = x;
#pragma unroll
  for (int off = 1; off < 64; off <<= 1) {
    int y = __shfl_up(inc, off, 64);
    if (lane >= off) inc += y;
  }
  if (lane == 63) ws[w] = inc;
  __syncthreads();
  if (threadIdx.x == 0) {
    int t = 0;
#pragma unroll
    for (int k = 0; k < 16; ++k) { woff[k] = t; t += ws[k]; }
  }
  __syncthreads();
  int excl = inc - x + woff[w] + bsum[blockIdx.x];
  if (i < n) rowptr[i] = excl;
  if (i == n - 1) rowptr[n] = excl + x;
}

// score + CSR scatter fused; packed 8B records
__global__ void k_csr(const int* __restrict__ ei, const float* __restrict__ a,
                      const float* __restrict__ b, const int* __restrict__ rowptr,
                      int* __restrict__ cursor, EdgeRec* __restrict__ csr, int n_edges) {
  int e = blockIdx.x * blockDim.x + threadIdx.x;
  if (e >= n_edges) return;
  int src = ei[e];
  int dst = ei[n_edges + e];
  float s = a[src] + b[dst];
  float sc = s > 0.f ? s : 0.01f * s;   // LeakyReLU(0.01)
  int slot = atomicAdd(cursor + src, 1);
  EdgeRec er; er.d = dst; er.s = sc;
  csr[rowptr[src] + slot] = er;
}

// Per node (1 wave): 4 edges/iter, 16 lanes x float4 per v-row.
__global__ __launch_bounds__(256) void k_agg(
    const int* __restrict__ rowptr, const EdgeRec* __restrict__ csr,
    const float* __restrict__ v, const float* __restrict__ Wproj,
    const float* __restrict__ xH, float* __restrict__ out, int n_nodes) {
  __shared__ float om_s[4][64];
  int wib = threadIdx.x >> 6;
  int lane = threadIdx.x & 63;
  int n = blockIdx.x * 4 + wib;
  if (n >= n_nodes) return;            // wave-uniform

  int r0 = rowptr[n], r1 = rowptr[n + 1];
  int g = lane >> 4, l16 = lane & 15;
  float4 acc = make_float4(0.f, 0.f, 0.f, 0.f);
  float ssum = 0.f;
  for (int i = r0 + g; i < r1; i += 4) {
    EdgeRec er = csr[i];
    float wgt = __expf(er.s);
    ssum += wgt;
    float4 vv = ((const float4*)(v + (size_t)er.d * 64))[l16];
    acc.x = fmaf(wgt, vv.x, acc.x);
    acc.y = fmaf(wgt, vv.y, acc.y);
    acc.z = fmaf(wgt, vv.z, acc.z);
    acc.w = fmaf(wgt, vv.w, acc.w);
  }
  // sum the 4 groups (ssum identical within group -> same reduce is exact)
#pragma unroll
  for (int off = 16; off < 64; off <<= 1) {
    acc.x += __shfl_xor(acc.x, off, 64);
    acc.y += __shfl_xor(acc.y, off, 64);
    acc.z += __shfl_xor(acc.z, off, 64);
    acc.w += __shfl_xor(acc.w, off, 64);
    ssum  += __shfl_xor(ssum,  off, 64);
  }
  if (r1 > r0) {
    float is = 1.f / ssum;
    acc.x *= is; acc.y *= is; acc.z *= is; acc.w *= is;
  }
  if (l16 == 0) acc.x += 1.0f;         // origin (dim 0)

  float s2 = acc.x * acc.x + acc.y * acc.y + acc.z * acc.z + acc.w * acc.w;
#pragma unroll
  for (int off = 1; off < 16; off <<= 1) s2 += __shfl_xor(s2, off, 64);
  float o0 = __shfl(acc.x, 0, 64);
  float inner = s2 - 2.f * o0 * o0;
  float sc = 1.f / sqrtf(fmaxf(fabsf(inner), 1e-8f));
  if (g == 0)
    ((float4*)om_s[wib])[l16] = make_float4(acc.x * sc, acc.y * sc, acc.z * sc, acc.w * sc);
  // same-wave LDS dependency only; compiler inserts the wait

  // x = to_manifold(om @ Wproj^T): lane -> out dims {lane, lane+64}
  float p0 = 0.f, p1 = 0.f;
  const float4* om4 = (const float4*)om_s[wib];
  const float4* wpa = (const float4*)(Wproj + (size_t)lane * 64);
  const float4* wpb = (const float4*)(Wproj + (size_t)(lane + 64) * 64);
#pragma unroll
  for (int t4 = 0; t4 < 16; ++t4) {
    float4 o4 = om4[t4];
    float4 wa = wpa[t4];
    float4 wb = wpb[t4];
    p0 = fmaf(o4.x, wa.x, fmaf(o4.y, wa.y, fmaf(o4.z, wa.z, fmaf(o4.w, wa.w, p0))));
    p1 = fmaf(o4.x, wb.x, fmaf(o4.y, wb.y, fmaf(o4.z, wb.z, fmaf(o4.w, wb.w, p1))));
  }
  float s2p = p0 * p0 + p1 * p1;
#pragma unroll
  for (int off = 1; off < 64; off <<= 1) s2p += __shfl_xor(s2p, off, 64);
  float p00 = __shfl(p0, 0, 64);
  float innerp = s2p - 2.f * p00 * p00;
  float invp = 1.f / sqrtf(fmaxf(fabsf(innerp), 1e-8f));
  float x0 = p0 * invp;
  float x1 = p1 * invp;

  float z0 = x0 + xH[(size_t)n * 128 + lane];
  float z1 = x1 + xH[(size_t)n * 128 + 64 + lane];
  float s2z = z0 * z0 + z1 * z1;
#pragma unroll
  for (int off = 1; off < 64; off <<= 1) s2z += __shfl_xor(s2z, off, 64);
  float zz0 = __shfl(z0, 0, 64);
  float innerz = s2z - 2.f * zz0 * zz0;
  float invz = 1.f / sqrtf(fmaxf(fabsf(innerz), 1e-8f));
  out[(size_t)n * 128 + lane] = z0 * invz;
  out[(size_t)n * 128 + 64 + lane] = z1 * invz;
}

extern "C" void kernel_launch(void* const* d_in, const int* in_sizes, int n_in,
                              void* d_out, int out_size, void* d_ws, size_t ws_size,
                              hipStream_t stream) {
  const float* xH    = (const float*)d_in[0];
  const float* xS    = (const float*)d_in[1];
  const int*   ei    = (const int*)d_in[2];
  const float* Wq    = (const float*)d_in[3];
  const float* Wk    = (const float*)d_in[4];
  const float* Wv    = (const float*)d_in[5];
  const float* Ws    = (const float*)d_in[6];
  const float* Wproj = (const float*)d_in[7];
  float* out = (float*)d_out;

  int N = in_sizes[0] / 128;
  int E = in_sizes[2] / 2;

  char* ws = (char*)d_ws;
  size_t off = 0;
  auto alloc = [&](size_t bytes) {
    void* p = ws + off;
    off = (off + bytes + 255) & ~(size_t)255;
    return p;
  };
  float*   a      = (float*)alloc((size_t)N * 4);
  float*   b      = (float*)alloc((size_t)N * 4);
  float*   v      = (float*)alloc((size_t)N * 64 * 4);
  EdgeRec* csr    = (EdgeRec*)alloc((size_t)E * 8);
  int*     deg    = (int*)alloc((size_t)N * 4);
  int*     cursor = (int*)alloc((size_t)N * 4);
  int*     rowptr = (int*)alloc((size_t)(N + 1) * 4);
  int*     bsum   = (int*)alloc(64 * 4);

  int nb = (N + 1023) / 1024;   // 49 <= 64

  k_init<<<(N + 255) / 256, 256, 0, stream>>>(deg, cursor, N);

  int n_tiles = (N + 63) / 64;
  int n_waves = 3 * n_tiles;
  k_linear<<<(n_waves + 3) / 4, 256, 0, stream>>>(xH, xS, Wq, Wk, Wv, Ws, a, b, v, N, n_tiles);

  k_deg<<<(E + 255) / 256, 256, 0, stream>>>(ei, deg, E);

  k_scan1<<<nb, 1024, 0, stream>>>(deg, bsum, N);
  k_scan2<<<1, 64, 0, stream>>>(bsum, nb);
  k_scan3<<<nb, 1024, 0, stream>>>(deg, bsum, rowptr, N);

  k_csr<<<(E + 255) / 256, 256, 0, stream>>>(ei, a, b, rowptr, cursor, csr, E);

  k_agg<<<(N + 3) / 4, 256, 0, stream>>>(rowptr, csr, v, Wproj, xH, out, N);
}

// Round 3
// 397.608 us; speedup vs baseline: 1.6950x; 1.2525x over previous
//
#include <hip/hip_runtime.h>
#include <math.h>

struct __align__(8) EdgeRec { int d; float s; };

__global__ void k_init(int* __restrict__ deg, int* __restrict__ cursor, int n) {
  int i = blockIdx.x * blockDim.x + threadIdx.x;
  if (i < n) { deg[i] = 0; cursor[i] = 0; }
}

// Transposed linear: lane = node. acc[64] per lane; W via uniform (scalar) loads.
// m=0: a[n] = Ws[0:64] . norm(xS@Wq^T)
// m=1: b[n] = Ws[64:128] . norm(xH@Wk^T)
// m=2: v[n] = norm(xH@Wv^T)
__global__ __launch_bounds__(256, 2) void k_linear(
    const float* __restrict__ xH, const float* __restrict__ xS,
    const float* __restrict__ Wq, const float* __restrict__ Wk,
    const float* __restrict__ Wv, const float* __restrict__ Ws,
    float* __restrict__ a, float* __restrict__ b, float* __restrict__ v,
    int n_nodes, int n_tiles) {
  int wid = __builtin_amdgcn_readfirstlane((blockIdx.x * blockDim.x + threadIdx.x) >> 6);
  if (wid >= 3 * n_tiles) return;
  int lane = threadIdx.x & 63;
  int m = wid / n_tiles;           // uniform
  int tile = wid - m * n_tiles;
  int n = tile * 64 + lane;
  if (n >= n_nodes) n = n_nodes - 1;  // clamped dups write identical values

  const float* X = (m == 0) ? xS : xH;
  const float* W = (m == 0) ? Wq : (m == 1) ? Wk : Wv;
  const float* xrow = X + (size_t)n * 128;

  float acc[64];
#pragma unroll
  for (int d = 0; d < 64; ++d) acc[d] = 0.f;

  for (int c = 0; c < 4; ++c) {       // j-chunks of 32
    float xr[32];
    const float4* xp = (const float4*)(xrow + c * 32);
#pragma unroll
    for (int q4 = 0; q4 < 8; ++q4) {
      float4 t = xp[q4];
      xr[4 * q4 + 0] = t.x; xr[4 * q4 + 1] = t.y;
      xr[4 * q4 + 2] = t.z; xr[4 * q4 + 3] = t.w;
    }
    const float* wbase = W + c * 32;  // uniform -> s_load
#pragma unroll
    for (int d = 0; d < 64; ++d) {
#pragma unroll
      for (int jj = 0; jj < 32; ++jj)
        acc[d] = fmaf(wbase[d * 128 + jj], xr[jj], acc[d]);
    }
  }

  float s2 = 0.f;
#pragma unroll
  for (int d = 0; d < 64; ++d) s2 = fmaf(acc[d], acc[d], s2);
  float inner = s2 - 2.f * acc[0] * acc[0];          // Lorentz inner
  float inv = 1.f / sqrtf(fmaxf(fabsf(inner), 1e-8f));

  if (m == 2) {
    float4* vp = (float4*)(v + (size_t)n * 64);
#pragma unroll
    for (int d4 = 0; d4 < 16; ++d4)
      vp[d4] = make_float4(acc[4 * d4] * inv, acc[4 * d4 + 1] * inv,
                           acc[4 * d4 + 2] * inv, acc[4 * d4 + 3] * inv);
  } else {
    const float* wsrow = Ws + (m == 1 ? 64 : 0);     // uniform -> s_load
    float r = 0.f;
#pragma unroll
    for (int d = 0; d < 64; ++d) r = fmaf(acc[d], wsrow[d], r);
    (m == 0 ? a : b)[n] = r * inv;
  }
}

__global__ void k_deg(const int* __restrict__ ei, int* __restrict__ deg, int n_edges) {
  int e = blockIdx.x * blockDim.x + threadIdx.x;
  if (e < n_edges) atomicAdd(deg + ei[e], 1);
}

// ---- 3-phase block scan: deg -> rowptr (exclusive) ----
__global__ __launch_bounds__(1024) void k_scan1(const int* __restrict__ deg,
                                                int* __restrict__ bsum, int n) {
  __shared__ int ws[16];
  int i = blockIdx.x * 1024 + threadIdx.x;
  int x = (i < n) ? deg[i] : 0;
  int s = x;
#pragma unroll
  for (int off = 1; off < 64; off <<= 1) s += __shfl_xor(s, off, 64);
  if ((threadIdx.x & 63) == 0) ws[threadIdx.x >> 6] = s;
  __syncthreads();
  if (threadIdx.x == 0) {
    int t = 0;
#pragma unroll
    for (int k = 0; k < 16; ++k) t += ws[k];
    bsum[blockIdx.x] = t;
  }
}

__global__ void k_scan2(int* __restrict__ bsum, int nb) {  // 1 wave, nb<=64
  int lane = threadIdx.x;
  int orig = (lane < nb) ? bsum[lane] : 0;
  int x = orig;
#pragma unroll
  for (int off = 1; off < 64; off <<= 1) {
    int y = __shfl_up(x, off, 64);
    if (lane >= off) x += y;
  }
  if (lane < nb) bsum[lane] = x - orig;  // exclusive
}

__global__ __launch_bounds__(1024) void k_scan3(const int* __restrict__ deg,
                                                const int* __restrict__ bsum,
                                                int* __restrict__ rowptr, int n) {
  __shared__ int ws[16];
  __shared__ int woff[16];
  int i = blockIdx.x * 1024 + threadIdx.x;
  int lane = threadIdx.x & 63, w = threadIdx.x >> 6;
  int x = (i < n) ? deg[i] : 0;
  int inc = x;
#pragma unroll
  for (int off = 1; off < 64; off <<= 1) {
    int y = __shfl_up(inc, off, 64);
    if (lane >= off) inc += y;
  }
  if (lane == 63) ws[w] = inc;
  __syncthreads();
  if (threadIdx.x == 0) {
    int t = 0;
#pragma unroll
    for (int k = 0; k < 16; ++k) { woff[k] = t; t += ws[k]; }
  }
  __syncthreads();
  int excl = inc - x + woff[w] + bsum[blockIdx.x];
  if (i < n) rowptr[i] = excl;
  if (i == n - 1) rowptr[n] = excl + x;
}

// score + CSR scatter fused; packed 8B records
__global__ void k_csr(const int* __restrict__ ei, const float* __restrict__ a,
                      const float* __restrict__ b, const int* __restrict__ rowptr,
                      int* __restrict__ cursor, EdgeRec* __restrict__ csr, int n_edges) {
  int e = blockIdx.x * blockDim.x + threadIdx.x;
  if (e >= n_edges) return;
  int src = ei[e];
  int dst = ei[n_edges + e];
  float s = a[src] + b[dst];
  float sc = s > 0.f ? s : 0.01f * s;   // LeakyReLU(0.01)
  int slot = atomicAdd(cursor + src, 1);
  EdgeRec er; er.d = dst; er.s = sc;
  csr[rowptr[src] + slot] = er;
}

// Wave per node: coalesced csr prefetch -> unrolled independent v gathers.
// Writes om[n][64] = to_manifold(origin + softmax-agg of v).
__global__ __launch_bounds__(256) void k_agg1(
    const int* __restrict__ rowptr, const EdgeRec* __restrict__ csr,
    const float* __restrict__ v, float* __restrict__ om, int n_nodes) {
  int wib = threadIdx.x >> 6;
  int lane = threadIdx.x & 63;
  int n = blockIdx.x * 4 + wib;
  if (n >= n_nodes) return;            // wave-uniform

  int r0 = rowptr[n], r1 = rowptr[n + 1];
  int g = lane >> 4, l16 = lane & 15;
  float4 acc = make_float4(0.f, 0.f, 0.f, 0.f);
  float ssl = 0.f;                     // per-lane exp sum

  for (int base = r0; base < r1; base += 64) {
    int cnt = r1 - base; if (cnt > 64) cnt = 64;
    int erd = 0; float wl = 0.f;
    if (lane < cnt) {
      EdgeRec er = csr[base + lane];   // one coalesced 512B load
      erd = er.d;
      wl = __expf(er.s);
    }
    ssl += wl;
#pragma unroll
    for (int j = 0; j < 16; ++j) {
      int idx = g + 4 * j;             // uniform within 16-lane group
      int d = __shfl(erd, idx, 64);
      float w = __shfl(wl, idx, 64);
      if (idx < cnt) {
        float4 vv = ((const float4*)(v + (size_t)d * 64))[l16];
        acc.x = fmaf(w, vv.x, acc.x);
        acc.y = fmaf(w, vv.y, acc.y);
        acc.z = fmaf(w, vv.z, acc.z);
        acc.w = fmaf(w, vv.w, acc.w);
      }
    }
  }

  // reduce 4 groups + exp-sum across wave
#pragma unroll
  for (int off = 16; off < 64; off <<= 1) {
    acc.x += __shfl_xor(acc.x, off, 64);
    acc.y += __shfl_xor(acc.y, off, 64);
    acc.z += __shfl_xor(acc.z, off, 64);
    acc.w += __shfl_xor(acc.w, off, 64);
  }
#pragma unroll
  for (int off = 1; off < 64; off <<= 1) ssl += __shfl_xor(ssl, off, 64);

  if (r1 > r0) {
    float is = 1.f / ssl;
    acc.x *= is; acc.y *= is; acc.z *= is; acc.w *= is;
  }
  if (l16 == 0) acc.x += 1.0f;         // origin (dim 0)

  float s2 = acc.x * acc.x + acc.y * acc.y + acc.z * acc.z + acc.w * acc.w;
#pragma unroll
  for (int off = 1; off < 16; off <<= 1) s2 += __shfl_xor(s2, off, 64);
  float o0 = __shfl(acc.x, 0, 64);
  float inner = s2 - 2.f * o0 * o0;
  float sc = 1.f / sqrtf(fmaxf(fabsf(inner), 1e-8f));
  if (g == 0)
    ((float4*)(om + (size_t)n * 64))[l16] =
        make_float4(acc.x * sc, acc.y * sc, acc.z * sc, acc.w * sc);
}

// Transposed projection: lane = node. p = om@Wproj^T (128), x = norm(p),
// z = norm(x + xH). Wproj via uniform s_loads.
__global__ __launch_bounds__(256, 1) void k_proj(
    const float* __restrict__ om, const float* __restrict__ Wp,
    const float* __restrict__ xH, float* __restrict__ out, int n_nodes) {
  int gid = blockIdx.x * 256 + threadIdx.x;
  int n = gid < n_nodes ? gid : n_nodes - 1;   // dup lanes write identical data
  const float* orow = om + (size_t)n * 64;

  float acc0[64], acc1[64];
#pragma unroll
  for (int d = 0; d < 64; ++d) { acc0[d] = 0.f; acc1[d] = 0.f; }

#pragma unroll
  for (int c = 0; c < 2; ++c) {
    float xr[32];
    const float4* xp = (const float4*)(orow + c * 32);
#pragma unroll
    for (int q = 0; q < 8; ++q) {
      float4 t = xp[q];
      xr[4 * q] = t.x; xr[4 * q + 1] = t.y; xr[4 * q + 2] = t.z; xr[4 * q + 3] = t.w;
    }
    const float* wb = Wp + c * 32;    // uniform -> s_load
#pragma unroll
    for (int d = 0; d < 64; ++d) {
#pragma unroll
      for (int jj = 0; jj < 32; ++jj) {
        acc0[d] = fmaf(wb[d * 64 + jj], xr[jj], acc0[d]);
        acc1[d] = fmaf(wb[(d + 64) * 64 + jj], xr[jj], acc1[d]);
      }
    }
  }

  float s2 = 0.f;
#pragma unroll
  for (int d = 0; d < 64; ++d) s2 = fmaf(acc0[d], acc0[d], fmaf(acc1[d], acc1[d], s2));
  float innerp = s2 - 2.f * acc0[0] * acc0[0];
  float invp = 1.f / sqrtf(fmaxf(fabsf(innerp), 1e-8f));

  const float* xrow = xH + (size_t)n * 128;
  float s2z = 0.f;
#pragma unroll
  for (int c = 0; c < 4; ++c) {
    float xr[32];
    const float4* xp = (const float4*)(xrow + c * 32);
#pragma unroll
    for (int q = 0; q < 8; ++q) {
      float4 t = xp[q];
      xr[4 * q] = t.x; xr[4 * q + 1] = t.y; xr[4 * q + 2] = t.z; xr[4 * q + 3] = t.w;
    }
#pragma unroll
    for (int jj = 0; jj < 32; ++jj) {
      float z;
      if (c < 2) { z = fmaf(acc0[c * 32 + jj], invp, xr[jj]); acc0[c * 32 + jj] = z; }
      else       { z = fmaf(acc1[(c - 2) * 32 + jj], invp, xr[jj]); acc1[(c - 2) * 32 + jj] = z; }
      s2z = fmaf(z, z, s2z);
    }
  }
  float innerz = s2z - 2.f * acc0[0] * acc0[0];
  float invz = 1.f / sqrtf(fmaxf(fabsf(innerz), 1e-8f));

  float4* orow_out = (float4*)(out + (size_t)n * 128);
#pragma unroll
  for (int q = 0; q < 16; ++q)
    orow_out[q] = make_float4(acc0[4 * q] * invz, acc0[4 * q + 1] * invz,
                              acc0[4 * q + 2] * invz, acc0[4 * q + 3] * invz);
#pragma unroll
  for (int q = 0; q < 16; ++q)
    orow_out[16 + q] = make_float4(acc1[4 * q] * invz, acc1[4 * q + 1] * invz,
                                   acc1[4 * q + 2] * invz, acc1[4 * q + 3] * invz);
}

extern "C" void kernel_launch(void* const* d_in, const int* in_sizes, int n_in,
                              void* d_out, int out_size, void* d_ws, size_t ws_size,
                              hipStream_t stream) {
  const float* xH    = (const float*)d_in[0];
  const float* xS    = (const float*)d_in[1];
  const int*   ei    = (const int*)d_in[2];
  const float* Wq    = (const float*)d_in[3];
  const float* Wk    = (const float*)d_in[4];
  const float* Wv    = (const float*)d_in[5];
  const float* Ws    = (const float*)d_in[6];
  const float* Wproj = (const float*)d_in[7];
  float* out = (float*)d_out;

  int N = in_sizes[0] / 128;
  int E = in_sizes[2] / 2;

  char* ws = (char*)d_ws;
  size_t off = 0;
  auto alloc = [&](size_t bytes) {
    void* p = ws + off;
    off = (off + bytes + 255) & ~(size_t)255;
    return p;
  };
  float*   a      = (float*)alloc((size_t)N * 4);
  float*   b      = (float*)alloc((size_t)N * 4);
  float*   v      = (float*)alloc((size_t)N * 64 * 4);
  float*   om     = (float*)alloc((size_t)N * 64 * 4);
  EdgeRec* csr    = (EdgeRec*)alloc((size_t)E * 8);
  int*     deg    = (int*)alloc((size_t)N * 4);
  int*     cursor = (int*)alloc((size_t)N * 4);
  int*     rowptr = (int*)alloc((size_t)(N + 1) * 4);
  int*     bsum   = (int*)alloc(64 * 4);

  int nb = (N + 1023) / 1024;   // 49 <= 64

  k_init<<<(N + 255) / 256, 256, 0, stream>>>(deg, cursor, N);

  int n_tiles = (N + 63) / 64;
  int n_waves = 3 * n_tiles;
  k_linear<<<(n_waves + 3) / 4, 256, 0, stream>>>(xH, xS, Wq, Wk, Wv, Ws, a, b, v, N, n_tiles);

  k_deg<<<(E + 255) / 256, 256, 0, stream>>>(ei, deg, E);

  k_scan1<<<nb, 1024, 0, stream>>>(deg, bsum, N);
  k_scan2<<<1, 64, 0, stream>>>(bsum, nb);
  k_scan3<<<nb, 1024, 0, stream>>>(deg, bsum, rowptr, N);

  k_csr<<<(E + 255) / 256, 256, 0, stream>>>(ei, a, b, rowptr, cursor, csr, E);

  k_agg1<<<(N + 3) / 4, 256, 0, stream>>>(rowptr, csr, v, om, N);

  k_proj<<<(N + 255) / 256, 256, 0, stream>>>(om, Wproj, xH, out, N);
}

// Round 4
// 268.433 us; speedup vs baseline: 2.5107x; 1.4812x over previous
//
#include <hip/hip_runtime.h>
#include <math.h>

typedef __attribute__((ext_vector_type(8))) __bf16 bf16x8;
typedef __attribute__((ext_vector_type(4))) float f32x4;
typedef unsigned short u16;

struct __align__(8) EdgeRec { int d; float s; };

__global__ void k_init(int* __restrict__ deg, int* __restrict__ cursor, int n) {
  int i = blockIdx.x * blockDim.x + threadIdx.x;
  if (i < n) { deg[i] = 0; cursor[i] = 0; }
}

// Convert Wcat = [Wq;Wk;Wv] (192x128 f32) into hi/lo bf16 planes (truncate split).
__global__ void k_wprep(const float* __restrict__ Wq, const float* __restrict__ Wk,
                        const float* __restrict__ Wv, u16* __restrict__ Whi,
                        u16* __restrict__ Wlo) {
  int i = blockIdx.x * 256 + threadIdx.x;
  if (i >= 192 * 128) return;
  int r = i >> 7, c = i & 127;
  float x = (r < 64) ? Wq[r * 128 + c] : (r < 128) ? Wk[(r - 64) * 128 + c]
                                                   : Wv[(r - 128) * 128 + c];
  unsigned u = __float_as_uint(x);
  unsigned hb = u & 0xffff0000u;
  float lo = x - __uint_as_float(hb);
  Whi[i] = (u16)(u >> 16);
  Wlo[i] = (u16)(__float_as_uint(lo) >> 16);
}

__device__ __forceinline__ void packhl(float4 f0, float4 f1, bf16x8* ph, bf16x8* pl) {
  float xv[8] = {f0.x, f0.y, f0.z, f0.w, f1.x, f1.y, f1.z, f1.w};
  union { u16 u[8]; bf16x8 v; } H, L;
#pragma unroll
  for (int e = 0; e < 8; ++e) {
    unsigned u = __float_as_uint(xv[e]);
    unsigned hb = u & 0xffff0000u;
    float lo = xv[e] - __uint_as_float(hb);
    H.u[e] = (u16)(u >> 16);
    L.u[e] = (u16)(__float_as_uint(lo) >> 16);
  }
  *ph = H.v; *pl = L.v;
}

// MFMA linear: C[64 nodes x 192 outs] per block (4 waves, 16 rows each).
// cols 0..63=q (A from xS), 64..127=k, 128..191=v (A from xH).
// Split-bf16: C = Ah*Bh + Al*Bh + Ah*Bl.
__global__ __launch_bounds__(256, 3) void k_lin_mfma(
    const float* __restrict__ xH, const float* __restrict__ xS,
    const u16* __restrict__ Whi, const u16* __restrict__ Wlo,
    const float* __restrict__ Ws, float* __restrict__ a, float* __restrict__ b,
    float* __restrict__ v, int n_nodes) {
  int w = threadIdx.x >> 6;
  int lane = threadIdx.x & 63;
  int col = lane & 15;   // A-row / B-col within tile
  int kg = lane >> 4;    // k-group (8 elems each)
  int n0w = blockIdx.x * 64 + w * 16;
  int arow = n0w + col; if (arow >= n_nodes) arow = n_nodes - 1;

  const float* xh = xH + (size_t)arow * 128;
  const float* xs = xS + (size_t)arow * 128;

  f32x4 acc[12];
#pragma unroll
  for (int t = 0; t < 12; ++t) acc[t] = (f32x4){0.f, 0.f, 0.f, 0.f};

#pragma unroll
  for (int ks = 0; ks < 4; ++ks) {
    int ko = ks * 32 + kg * 8;
    bf16x8 aSh, aSl, aHh, aHl;
    packhl(*(const float4*)(xs + ko), *(const float4*)(xs + ko + 4), &aSh, &aSl);
    packhl(*(const float4*)(xh + ko), *(const float4*)(xh + ko + 4), &aHh, &aHl);
#pragma unroll
    for (int t = 0; t < 12; ++t) {
      size_t woff = (size_t)(16 * t + col) * 128 + ko;
      bf16x8 bh = *(const bf16x8*)(Whi + woff);
      bf16x8 bl = *(const bf16x8*)(Wlo + woff);
      bf16x8 ah = (t < 4) ? aSh : aHh;
      bf16x8 al = (t < 4) ? aSl : aHl;
      acc[t] = __builtin_amdgcn_mfma_f32_16x16x32_bf16(ah, bh, acc[t], 0, 0, 0);
      acc[t] = __builtin_amdgcn_mfma_f32_16x16x32_bf16(al, bh, acc[t], 0, 0, 0);
      acc[t] = __builtin_amdgcn_mfma_f32_16x16x32_bf16(ah, bl, acc[t], 0, 0, 0);
    }
  }

  // epilogue: row r = kg*4 + j held at reg j, col = lane&15 per tile
  float wsq[4], wsk[4];
#pragma unroll
  for (int t = 0; t < 4; ++t) { wsq[t] = Ws[16 * t + col]; wsk[t] = Ws[64 + 16 * t + col]; }

#pragma unroll
  for (int j = 0; j < 4; ++j) {
    float q2 = 0.f, k2 = 0.f, v2 = 0.f, aj = 0.f, bj = 0.f;
#pragma unroll
    for (int t = 0; t < 4; ++t) {
      float cq = acc[t][j];     q2 = fmaf(cq, cq, q2); aj = fmaf(cq, wsq[t], aj);
      float ck = acc[t + 4][j]; k2 = fmaf(ck, ck, k2); bj = fmaf(ck, wsk[t], bj);
      float cv = acc[t + 8][j]; v2 = fmaf(cv, cv, v2);
    }
#pragma unroll
    for (int off = 1; off < 16; off <<= 1) {
      q2 += __shfl_xor(q2, off, 64);
      k2 += __shfl_xor(k2, off, 64);
      v2 += __shfl_xor(v2, off, 64);
      aj += __shfl_xor(aj, off, 64);
      bj += __shfl_xor(bj, off, 64);
    }
    int gbase = lane & 48;
    float q0 = __shfl(acc[0][j], gbase, 64);
    float k0 = __shfl(acc[4][j], gbase, 64);
    float v0 = __shfl(acc[8][j], gbase, 64);
    float invq = 1.f / sqrtf(fmaxf(fabsf(q2 - 2.f * q0 * q0), 1e-8f));
    float invk = 1.f / sqrtf(fmaxf(fabsf(k2 - 2.f * k0 * k0), 1e-8f));
    float invv = 1.f / sqrtf(fmaxf(fabsf(v2 - 2.f * v0 * v0), 1e-8f));
    int node = n0w + kg * 4 + j; if (node >= n_nodes) node = n_nodes - 1;
    if (col == 0) { a[node] = aj * invq; b[node] = bj * invk; }
#pragma unroll
    for (int t = 0; t < 4; ++t)
      v[(size_t)node * 64 + t * 16 + col] = acc[t + 8][j] * invv;
  }
}

__global__ void k_deg(const int* __restrict__ ei, int* __restrict__ deg, int n_edges) {
  int e = blockIdx.x * blockDim.x + threadIdx.x;
  if (e < n_edges) atomicAdd(deg + ei[e], 1);
}

// ---- 3-phase block scan: deg -> rowptr (exclusive) ----
__global__ __launch_bounds__(1024) void k_scan1(const int* __restrict__ deg,
                                                int* __restrict__ bsum, int n) {
  __shared__ int ws[16];
  int i = blockIdx.x * 1024 + threadIdx.x;
  int x = (i < n) ? deg[i] : 0;
  int s = x;
#pragma unroll
  for (int off = 1; off < 64; off <<= 1) s += __shfl_xor(s, off, 64);
  if ((threadIdx.x & 63) == 0) ws[threadIdx.x >> 6] = s;
  __syncthreads();
  if (threadIdx.x == 0) {
    int t = 0;
#pragma unroll
    for (int k = 0; k < 16; ++k) t += ws[k];
    bsum[blockIdx.x] = t;
  }
}

__global__ void k_scan2(int* __restrict__ bsum, int nb) {  // 1 wave, nb<=64
  int lane = threadIdx.x;
  int orig = (lane < nb) ? bsum[lane] : 0;
  int x = orig;
#pragma unroll
  for (int off = 1; off < 64; off <<= 1) {
    int y = __shfl_up(x, off, 64);
    if (lane >= off) x += y;
  }
  if (lane < nb) bsum[lane] = x - orig;  // exclusive
}

__global__ __launch_bounds__(1024) void k_scan3(const int* __restrict__ deg,
                                                const int* __restrict__ bsum,
                                                int* __restrict__ rowptr, int n) {
  __shared__ int ws[16];
  __shared__ int woff[16];
  int i = blockIdx.x * 1024 + threadIdx.x;
  int lane = threadIdx.x & 63, w = threadIdx.x >> 6;
  int x = (i < n) ? deg[i] : 0;
  int inc = x;
#pragma unroll
  for (int off = 1; off < 64; off <<= 1) {
    int y = __shfl_up(inc, off, 64);
    if (lane >= off) inc += y;
  }
  if (lane == 63) ws[w] = inc;
  __syncthreads();
  if (threadIdx.x == 0) {
    int t = 0;
#pragma unroll
    for (int k = 0; k < 16; ++k) { woff[k] = t; t += ws[k]; }
  }
  __syncthreads();
  int excl = inc - x + woff[w] + bsum[blockIdx.x];
  if (i < n) rowptr[i] = excl;
  if (i == n - 1) rowptr[n] = excl + x;
}

// score + CSR scatter fused; packed 8B records
__global__ void k_csr(const int* __restrict__ ei, const float* __restrict__ a,
                      const float* __restrict__ b, const int* __restrict__ rowptr,
                      int* __restrict__ cursor, EdgeRec* __restrict__ csr, int n_edges) {
  int e = blockIdx.x * blockDim.x + threadIdx.x;
  if (e >= n_edges) return;
  int src = ei[e];
  int dst = ei[n_edges + e];
  float s = a[src] + b[dst];
  float sc = s > 0.f ? s : 0.01f * s;   // LeakyReLU(0.01)
  int slot = atomicAdd(cursor + src, 1);
  EdgeRec er; er.d = dst; er.s = sc;
  csr[rowptr[src] + slot] = er;
}

// Wave per node: coalesced csr prefetch -> unrolled independent v gathers.
// Writes om[n][64] = to_manifold(origin + softmax-agg of v).
__global__ __launch_bounds__(256) void k_agg1(
    const int* __restrict__ rowptr, const EdgeRec* __restrict__ csr,
    const float* __restrict__ v, float* __restrict__ om, int n_nodes) {
  int wib = threadIdx.x >> 6;
  int lane = threadIdx.x & 63;
  int n = blockIdx.x * 4 + wib;
  if (n >= n_nodes) return;            // wave-uniform

  int r0 = rowptr[n], r1 = rowptr[n + 1];
  int g = lane >> 4, l16 = lane & 15;
  float4 acc = make_float4(0.f, 0.f, 0.f, 0.f);
  float ssl = 0.f;                     // per-lane exp sum

  for (int base = r0; base < r1; base += 64) {
    int cnt = r1 - base; if (cnt > 64) cnt = 64;
    int erd = 0; float wl = 0.f;
    if (lane < cnt) {
      EdgeRec er = csr[base + lane];   // one coalesced 512B load
      erd = er.d;
      wl = __expf(er.s);
    }
    ssl += wl;
#pragma unroll
    for (int j = 0; j < 16; ++j) {
      int idx = g + 4 * j;             // uniform within 16-lane group
      int d = __shfl(erd, idx, 64);
      float w = __shfl(wl, idx, 64);
      if (idx < cnt) {
        float4 vv = ((const float4*)(v + (size_t)d * 64))[l16];
        acc.x = fmaf(w, vv.x, acc.x);
        acc.y = fmaf(w, vv.y, acc.y);
        acc.z = fmaf(w, vv.z, acc.z);
        acc.w = fmaf(w, vv.w, acc.w);
      }
    }
  }

  // reduce 4 groups + exp-sum across wave
#pragma unroll
  for (int off = 16; off < 64; off <<= 1) {
    acc.x += __shfl_xor(acc.x, off, 64);
    acc.y += __shfl_xor(acc.y, off, 64);
    acc.z += __shfl_xor(acc.z, off, 64);
    acc.w += __shfl_xor(acc.w, off, 64);
  }
#pragma unroll
  for (int off = 1; off < 64; off <<= 1) ssl += __shfl_xor(ssl, off, 64);

  if (r1 > r0) {
    float is = 1.f / ssl;
    acc.x *= is; acc.y *= is; acc.z *= is; acc.w *= is;
  }
  if (l16 == 0) acc.x += 1.0f;         // origin (dim 0)

  float s2 = acc.x * acc.x + acc.y * acc.y + acc.z * acc.z + acc.w * acc.w;
#pragma unroll
  for (int off = 1; off < 16; off <<= 1) s2 += __shfl_xor(s2, off, 64);
  float o0 = __shfl(acc.x, 0, 64);
  float inner = s2 - 2.f * o0 * o0;
  float sc = 1.f / sqrtf(fmaxf(fabsf(inner), 1e-8f));
  if (g == 0)
    ((float4*)(om + (size_t)n * 64))[l16] =
        make_float4(acc.x * sc, acc.y * sc, acc.z * sc, acc.w * sc);
}

// Transposed projection: lane = node. p = om@Wproj^T (128), x = norm(p),
// z = norm(x + xH). Wproj via uniform s_loads.
__global__ __launch_bounds__(256, 1) void k_proj(
    const float* __restrict__ om, const float* __restrict__ Wp,
    const float* __restrict__ xH, float* __restrict__ out, int n_nodes) {
  int gid = blockIdx.x * 256 + threadIdx.x;
  int n = gid < n_nodes ? gid : n_nodes - 1;   // dup lanes write identical data
  const float* orow = om + (size_t)n * 64;

  float acc0[64], acc1[64];
#pragma unroll
  for (int d = 0; d < 64; ++d) { acc0[d] = 0.f; acc1[d] = 0.f; }

#pragma unroll
  for (int c = 0; c < 2; ++c) {
    float xr[32];
    const float4* xp = (const float4*)(orow + c * 32);
#pragma unroll
    for (int q = 0; q < 8; ++q) {
      float4 t = xp[q];
      xr[4 * q] = t.x; xr[4 * q + 1] = t.y; xr[4 * q + 2] = t.z; xr[4 * q + 3] = t.w;
    }
    const float* wb = Wp + c * 32;    // uniform -> s_load
#pragma unroll
    for (int d = 0; d < 64; ++d) {
#pragma unroll
      for (int jj = 0; jj < 32; ++jj) {
        acc0[d] = fmaf(wb[d * 64 + jj], xr[jj], acc0[d]);
        acc1[d] = fmaf(wb[(d + 64) * 64 + jj], xr[jj], acc1[d]);
      }
    }
  }

  float s2 = 0.f;
#pragma unroll
  for (int d = 0; d < 64; ++d) s2 = fmaf(acc0[d], acc0[d], fmaf(acc1[d], acc1[d], s2));
  float innerp = s2 - 2.f * acc0[0] * acc0[0];
  float invp = 1.f / sqrtf(fmaxf(fabsf(innerp), 1e-8f));

  const float* xrow = xH + (size_t)n * 128;
  float s2z = 0.f;
#pragma unroll
  for (int c = 0; c < 4; ++c) {
    float xr[32];
    const float4* xp = (const float4*)(xrow + c * 32);
#pragma unroll
    for (int q = 0; q < 8; ++q) {
      float4 t = xp[q];
      xr[4 * q] = t.x; xr[4 * q + 1] = t.y; xr[4 * q + 2] = t.z; xr[4 * q + 3] = t.w;
    }
#pragma unroll
    for (int jj = 0; jj < 32; ++jj) {
      float z;
      if (c < 2) { z = fmaf(acc0[c * 32 + jj], invp, xr[jj]); acc0[c * 32 + jj] = z; }
      else       { z = fmaf(acc1[(c - 2) * 32 + jj], invp, xr[jj]); acc1[(c - 2) * 32 + jj] = z; }
      s2z = fmaf(z, z, s2z);
    }
  }
  float innerz = s2z - 2.f * acc0[0] * acc0[0];
  float invz = 1.f / sqrtf(fmaxf(fabsf(innerz), 1e-8f));

  float4* orow_out = (float4*)(out + (size_t)n * 128);
#pragma unroll
  for (int q = 0; q < 16; ++q)
    orow_out[q] = make_float4(acc0[4 * q] * invz, acc0[4 * q + 1] * invz,
                              acc0[4 * q + 2] * invz, acc0[4 * q + 3] * invz);
#pragma unroll
  for (int q = 0; q < 16; ++q)
    orow_out[16 + q] = make_float4(acc1[4 * q] * invz, acc1[4 * q + 1] * invz,
                                   acc1[4 * q + 2] * invz, acc1[4 * q + 3] * invz);
}

extern "C" void kernel_launch(void* const* d_in, const int* in_sizes, int n_in,
                              void* d_out, int out_size, void* d_ws, size_t ws_size,
                              hipStream_t stream) {
  const float* xH    = (const float*)d_in[0];
  const float* xS    = (const float*)d_in[1];
  const int*   ei    = (const int*)d_in[2];
  const float* Wq    = (const float*)d_in[3];
  const float* Wk    = (const float*)d_in[4];
  const float* Wv    = (const float*)d_in[5];
  const float* Ws    = (const float*)d_in[6];
  const float* Wproj = (const float*)d_in[7];
  float* out = (float*)d_out;

  int N = in_sizes[0] / 128;
  int E = in_sizes[2] / 2;

  char* ws = (char*)d_ws;
  size_t off = 0;
  auto alloc = [&](size_t bytes) {
    void* p = ws + off;
    off = (off + bytes + 255) & ~(size_t)255;
    return p;
  };
  float*   a      = (float*)alloc((size_t)N * 4);
  float*   b      = (float*)alloc((size_t)N * 4);
  float*   v      = (float*)alloc((size_t)N * 64 * 4);
  float*   om     = (float*)alloc((size_t)N * 64 * 4);
  EdgeRec* csr    = (EdgeRec*)alloc((size_t)E * 8);
  int*     deg    = (int*)alloc((size_t)N * 4);
  int*     cursor = (int*)alloc((size_t)N * 4);
  int*     rowptr = (int*)alloc((size_t)(N + 1) * 4);
  int*     bsum   = (int*)alloc(64 * 4);
  u16*     Whi    = (u16*)alloc((size_t)192 * 128 * 2);
  u16*     Wlo    = (u16*)alloc((size_t)192 * 128 * 2);

  int nb = (N + 1023) / 1024;   // 49 <= 64

  k_init<<<(N + 255) / 256, 256, 0, stream>>>(deg, cursor, N);

  k_wprep<<<(192 * 128 + 255) / 256, 256, 0, stream>>>(Wq, Wk, Wv, Whi, Wlo);

  int n_tiles = (N + 63) / 64;
  k_lin_mfma<<<n_tiles, 256, 0, stream>>>(xH, xS, Whi, Wlo, Ws, a, b, v, N);

  k_deg<<<(E + 255) / 256, 256, 0, stream>>>(ei, deg, E);

  k_scan1<<<nb, 1024, 0, stream>>>(deg, bsum, N);
  k_scan2<<<1, 64, 0, stream>>>(bsum, nb);
  k_scan3<<<nb, 1024, 0, stream>>>(deg, bsum, rowptr, N);

  k_csr<<<(E + 255) / 256, 256, 0, stream>>>(ei, a, b, rowptr, cursor, csr, E);

  k_agg1<<<(N + 3) / 4, 256, 0, stream>>>(rowptr, csr, v, om, N);

  k_proj<<<(N + 255) / 256, 256, 0, stream>>>(om, Wproj, xH, out, N);
}

// Round 5
// 212.935 us; speedup vs baseline: 3.1651x; 1.2606x over previous
//
#include <hip/hip_runtime.h>
#include <math.h>

typedef __attribute__((ext_vector_type(8))) __bf16 bf16x8;
typedef __attribute__((ext_vector_type(4))) float f32x4;
typedef unsigned short u16;

struct __align__(8) EdgeRec { int d; float s; };

__global__ void k_init(int* __restrict__ deg, int* __restrict__ cursor, int n) {
  int i = blockIdx.x * blockDim.x + threadIdx.x;
  if (i < n) { deg[i] = 0; cursor[i] = 0; }
}

// Convert Wcat = [Wq;Wk;Wv] (192x128 f32) into hi/lo bf16 planes (truncate split).
__global__ void k_wprep(const float* __restrict__ Wq, const float* __restrict__ Wk,
                        const float* __restrict__ Wv, u16* __restrict__ Whi,
                        u16* __restrict__ Wlo) {
  int i = blockIdx.x * 256 + threadIdx.x;
  if (i >= 192 * 128) return;
  int r = i >> 7, c = i & 127;
  float x = (r < 64) ? Wq[r * 128 + c] : (r < 128) ? Wk[(r - 64) * 128 + c]
                                                   : Wv[(r - 128) * 128 + c];
  unsigned u = __float_as_uint(x);
  unsigned hb = u & 0xffff0000u;
  float lo = x - __uint_as_float(hb);
  Whi[i] = (u16)(u >> 16);
  Wlo[i] = (u16)(__float_as_uint(lo) >> 16);
}

// Wproj (128x64 f32) -> hi/lo bf16 planes
__global__ void k_wprep_p(const float* __restrict__ Wp, u16* __restrict__ Whi,
                          u16* __restrict__ Wlo) {
  int i = blockIdx.x * 256 + threadIdx.x;
  if (i >= 128 * 64) return;
  float x = Wp[i];
  unsigned u = __float_as_uint(x);
  unsigned hb = u & 0xffff0000u;
  float lo = x - __uint_as_float(hb);
  Whi[i] = (u16)(u >> 16);
  Wlo[i] = (u16)(__float_as_uint(lo) >> 16);
}

__device__ __forceinline__ void packhl(float4 f0, float4 f1, bf16x8* ph, bf16x8* pl) {
  float xv[8] = {f0.x, f0.y, f0.z, f0.w, f1.x, f1.y, f1.z, f1.w};
  union { u16 u[8]; bf16x8 v; } H, L;
#pragma unroll
  for (int e = 0; e < 8; ++e) {
    unsigned u = __float_as_uint(xv[e]);
    unsigned hb = u & 0xffff0000u;
    float lo = xv[e] - __uint_as_float(hb);
    H.u[e] = (u16)(u >> 16);
    L.u[e] = (u16)(__float_as_uint(lo) >> 16);
  }
  *ph = H.v; *pl = L.v;
}

// MFMA linear: C[64 nodes x 192 outs] per block (4 waves, 16 rows each).
// cols 0..63=q (A from xS), 64..127=k, 128..191=v (A from xH).
// Split-bf16: C = Ah*Bh + Al*Bh + Ah*Bl.
__global__ __launch_bounds__(256, 3) void k_lin_mfma(
    const float* __restrict__ xH, const float* __restrict__ xS,
    const u16* __restrict__ Whi, const u16* __restrict__ Wlo,
    const float* __restrict__ Ws, float* __restrict__ a, float* __restrict__ b,
    float* __restrict__ v, int n_nodes) {
  int w = threadIdx.x >> 6;
  int lane = threadIdx.x & 63;
  int col = lane & 15;   // A-row / B-col within tile
  int kg = lane >> 4;    // k-group (8 elems each)
  int n0w = blockIdx.x * 64 + w * 16;
  int arow = n0w + col; if (arow >= n_nodes) arow = n_nodes - 1;

  const float* xh = xH + (size_t)arow * 128;
  const float* xs = xS + (size_t)arow * 128;

  f32x4 acc[12];
#pragma unroll
  for (int t = 0; t < 12; ++t) acc[t] = (f32x4){0.f, 0.f, 0.f, 0.f};

#pragma unroll
  for (int ks = 0; ks < 4; ++ks) {
    int ko = ks * 32 + kg * 8;
    bf16x8 aSh, aSl, aHh, aHl;
    packhl(*(const float4*)(xs + ko), *(const float4*)(xs + ko + 4), &aSh, &aSl);
    packhl(*(const float4*)(xh + ko), *(const float4*)(xh + ko + 4), &aHh, &aHl);
#pragma unroll
    for (int t = 0; t < 12; ++t) {
      size_t woff = (size_t)(16 * t + col) * 128 + ko;
      bf16x8 bh = *(const bf16x8*)(Whi + woff);
      bf16x8 bl = *(const bf16x8*)(Wlo + woff);
      bf16x8 ah = (t < 4) ? aSh : aHh;
      bf16x8 al = (t < 4) ? aSl : aHl;
      acc[t] = __builtin_amdgcn_mfma_f32_16x16x32_bf16(ah, bh, acc[t], 0, 0, 0);
      acc[t] = __builtin_amdgcn_mfma_f32_16x16x32_bf16(al, bh, acc[t], 0, 0, 0);
      acc[t] = __builtin_amdgcn_mfma_f32_16x16x32_bf16(ah, bl, acc[t], 0, 0, 0);
    }
  }

  // epilogue: row r = kg*4 + j held at reg j, col = lane&15 per tile
  float wsq[4], wsk[4];
#pragma unroll
  for (int t = 0; t < 4; ++t) { wsq[t] = Ws[16 * t + col]; wsk[t] = Ws[64 + 16 * t + col]; }

#pragma unroll
  for (int j = 0; j < 4; ++j) {
    float q2 = 0.f, k2 = 0.f, v2 = 0.f, aj = 0.f, bj = 0.f;
#pragma unroll
    for (int t = 0; t < 4; ++t) {
      float cq = acc[t][j];     q2 = fmaf(cq, cq, q2); aj = fmaf(cq, wsq[t], aj);
      float ck = acc[t + 4][j]; k2 = fmaf(ck, ck, k2); bj = fmaf(ck, wsk[t], bj);
      float cv = acc[t + 8][j]; v2 = fmaf(cv, cv, v2);
    }
#pragma unroll
    for (int off = 1; off < 16; off <<= 1) {
      q2 += __shfl_xor(q2, off, 64);
      k2 += __shfl_xor(k2, off, 64);
      v2 += __shfl_xor(v2, off, 64);
      aj += __shfl_xor(aj, off, 64);
      bj += __shfl_xor(bj, off, 64);
    }
    int gbase = lane & 48;
    float q0 = __shfl(acc[0][j], gbase, 64);
    float k0 = __shfl(acc[4][j], gbase, 64);
    float v0 = __shfl(acc[8][j], gbase, 64);
    float invq = 1.f / sqrtf(fmaxf(fabsf(q2 - 2.f * q0 * q0), 1e-8f));
    float invk = 1.f / sqrtf(fmaxf(fabsf(k2 - 2.f * k0 * k0), 1e-8f));
    float invv = 1.f / sqrtf(fmaxf(fabsf(v2 - 2.f * v0 * v0), 1e-8f));
    int node = n0w + kg * 4 + j; if (node >= n_nodes) node = n_nodes - 1;
    if (col == 0) { a[node] = aj * invq; b[node] = bj * invk; }
#pragma unroll
    for (int t = 0; t < 4; ++t)
      v[(size_t)node * 64 + t * 16 + col] = acc[t + 8][j] * invv;
  }
}

__global__ void k_deg(const int* __restrict__ ei, int* __restrict__ deg, int n_edges) {
  int e = blockIdx.x * blockDim.x + threadIdx.x;
  if (e < n_edges) atomicAdd(deg + ei[e], 1);
}

// ---- 3-phase block scan: deg -> rowptr (exclusive) ----
__global__ __launch_bounds__(1024) void k_scan1(const int* __restrict__ deg,
                                                int* __restrict__ bsum, int n) {
  __shared__ int ws[16];
  int i = blockIdx.x * 1024 + threadIdx.x;
  int x = (i < n) ? deg[i] : 0;
  int s = x;
#pragma unroll
  for (int off = 1; off < 64; off <<= 1) s += __shfl_xor(s, off, 64);
  if ((threadIdx.x & 63) == 0) ws[threadIdx.x >> 6] = s;
  __syncthreads();
  if (threadIdx.x == 0) {
    int t = 0;
#pragma unroll
    for (int k = 0; k < 16; ++k) t += ws[k];
    bsum[blockIdx.x] = t;
  }
}

__global__ void k_scan2(int* __restrict__ bsum, int nb) {  // 1 wave, nb<=64
  int lane = threadIdx.x;
  int orig = (lane < nb) ? bsum[lane] : 0;
  int x = orig;
#pragma unroll
  for (int off = 1; off < 64; off <<= 1) {
    int y = __shfl_up(x, off, 64);
    if (lane >= off) x += y;
  }
  if (lane < nb) bsum[lane] = x - orig;  // exclusive
}

__global__ __launch_bounds__(1024) void k_scan3(const int* __restrict__ deg,
                                                const int* __restrict__ bsum,
                                                int* __restrict__ rowptr, int n) {
  __shared__ int ws[16];
  __shared__ int woff[16];
  int i = blockIdx.x * 1024 + threadIdx.x;
  int lane = threadIdx.x & 63, w = threadIdx.x >> 6;
  int x = (i < n) ? deg[i] : 0;
  int inc = x;
#pragma unroll
  for (int off = 1; off < 64; off <<= 1) {
    int y = __shfl_up(inc, off, 64);
    if (lane >= off) inc += y;
  }
  if (lane == 63) ws[w] = inc;
  __syncthreads();
  if (threadIdx.x == 0) {
    int t = 0;
#pragma unroll
    for (int k = 0; k < 16; ++k) { woff[k] = t; t += ws[k]; }
  }
  __syncthreads();
  int excl = inc - x + woff[w] + bsum[blockIdx.x];
  if (i < n) rowptr[i] = excl;
  if (i == n - 1) rowptr[n] = excl + x;
}

// score + CSR scatter fused; packed 8B records
__global__ void k_csr(const int* __restrict__ ei, const float* __restrict__ a,
                      const float* __restrict__ b, const int* __restrict__ rowptr,
                      int* __restrict__ cursor, EdgeRec* __restrict__ csr, int n_edges) {
  int e = blockIdx.x * blockDim.x + threadIdx.x;
  if (e >= n_edges) return;
  int src = ei[e];
  int dst = ei[n_edges + e];
  float s = a[src] + b[dst];
  float sc = s > 0.f ? s : 0.01f * s;   // LeakyReLU(0.01)
  int slot = atomicAdd(cursor + src, 1);
  EdgeRec er; er.d = dst; er.s = sc;
  csr[rowptr[src] + slot] = er;
}

// Wave per node: coalesced csr prefetch -> unrolled independent v gathers.
// Writes om[n][64] = to_manifold(origin + softmax-agg of v).
__global__ __launch_bounds__(256) void k_agg1(
    const int* __restrict__ rowptr, const EdgeRec* __restrict__ csr,
    const float* __restrict__ v, float* __restrict__ om, int n_nodes) {
  int wib = threadIdx.x >> 6;
  int lane = threadIdx.x & 63;
  int n = blockIdx.x * 4 + wib;
  if (n >= n_nodes) return;            // wave-uniform

  int r0 = rowptr[n], r1 = rowptr[n + 1];
  int g = lane >> 4, l16 = lane & 15;
  float4 acc = make_float4(0.f, 0.f, 0.f, 0.f);
  float ssl = 0.f;                     // per-lane exp sum

  for (int base = r0; base < r1; base += 64) {
    int cnt = r1 - base; if (cnt > 64) cnt = 64;
    int erd = 0; float wl = 0.f;
    if (lane < cnt) {
      EdgeRec er = csr[base + lane];   // one coalesced 512B load
      erd = er.d;
      wl = __expf(er.s);
    }
    ssl += wl;
#pragma unroll
    for (int j = 0; j < 16; ++j) {
      int idx = g + 4 * j;             // uniform within 16-lane group
      int d = __shfl(erd, idx, 64);
      float w = __shfl(wl, idx, 64);
      if (idx < cnt) {
        float4 vv = ((const float4*)(v + (size_t)d * 64))[l16];
        acc.x = fmaf(w, vv.x, acc.x);
        acc.y = fmaf(w, vv.y, acc.y);
        acc.z = fmaf(w, vv.z, acc.z);
        acc.w = fmaf(w, vv.w, acc.w);
      }
    }
  }

  // reduce 4 groups + exp-sum across wave
#pragma unroll
  for (int off = 16; off < 64; off <<= 1) {
    acc.x += __shfl_xor(acc.x, off, 64);
    acc.y += __shfl_xor(acc.y, off, 64);
    acc.z += __shfl_xor(acc.z, off, 64);
    acc.w += __shfl_xor(acc.w, off, 64);
  }
#pragma unroll
  for (int off = 1; off < 64; off <<= 1) ssl += __shfl_xor(ssl, off, 64);

  if (r1 > r0) {
    float is = 1.f / ssl;
    acc.x *= is; acc.y *= is; acc.z *= is; acc.w *= is;
  }
  if (l16 == 0) acc.x += 1.0f;         // origin (dim 0)

  float s2 = acc.x * acc.x + acc.y * acc.y + acc.z * acc.z + acc.w * acc.w;
#pragma unroll
  for (int off = 1; off < 16; off <<= 1) s2 += __shfl_xor(s2, off, 64);
  float o0 = __shfl(acc.x, 0, 64);
  float inner = s2 - 2.f * o0 * o0;
  float sc = 1.f / sqrtf(fmaxf(fabsf(inner), 1e-8f));
  if (g == 0)
    ((float4*)(om + (size_t)n * 64))[l16] =
        make_float4(acc.x * sc, acc.y * sc, acc.z * sc, acc.w * sc);
}

// MFMA projection: C[64 nodes x 128 outs] per block (4 waves, 16 rows each).
// p = om@Wproj^T, x = norm_L(p), z = norm_L(x + xH) -> out.
__global__ __launch_bounds__(256, 3) void k_proj_mfma(
    const float* __restrict__ om, const u16* __restrict__ Whi,
    const u16* __restrict__ Wlo, const float* __restrict__ xH,
    float* __restrict__ out, int n_nodes) {
  int w = threadIdx.x >> 6;
  int lane = threadIdx.x & 63;
  int col = lane & 15;
  int kg = lane >> 4;
  int n0w = blockIdx.x * 64 + w * 16;
  int arow = n0w + col; if (arow >= n_nodes) arow = n_nodes - 1;

  const float* orow = om + (size_t)arow * 64;

  f32x4 acc[8];
#pragma unroll
  for (int t = 0; t < 8; ++t) acc[t] = (f32x4){0.f, 0.f, 0.f, 0.f};

#pragma unroll
  for (int ks = 0; ks < 2; ++ks) {
    int ko = ks * 32 + kg * 8;
    bf16x8 ah, al;
    packhl(*(const float4*)(orow + ko), *(const float4*)(orow + ko + 4), &ah, &al);
#pragma unroll
    for (int t = 0; t < 8; ++t) {
      size_t woff = (size_t)(16 * t + col) * 64 + ko;
      bf16x8 bh = *(const bf16x8*)(Whi + woff);
      bf16x8 bl = *(const bf16x8*)(Wlo + woff);
      acc[t] = __builtin_amdgcn_mfma_f32_16x16x32_bf16(ah, bh, acc[t], 0, 0, 0);
      acc[t] = __builtin_amdgcn_mfma_f32_16x16x32_bf16(al, bh, acc[t], 0, 0, 0);
      acc[t] = __builtin_amdgcn_mfma_f32_16x16x32_bf16(ah, bl, acc[t], 0, 0, 0);
    }
  }

  int gbase = lane & 48;
#pragma unroll
  for (int j = 0; j < 4; ++j) {
    int node = n0w + kg * 4 + j; if (node >= n_nodes) node = n_nodes - 1;

    float s2p = 0.f;
#pragma unroll
    for (int t = 0; t < 8; ++t) s2p = fmaf(acc[t][j], acc[t][j], s2p);
#pragma unroll
    for (int off = 1; off < 16; off <<= 1) s2p += __shfl_xor(s2p, off, 64);
    float p0 = __shfl(acc[0][j], gbase, 64);
    float invp = 1.f / sqrtf(fmaxf(fabsf(s2p - 2.f * p0 * p0), 1e-8f));

    float z[8];
    float s2z = 0.f;
#pragma unroll
    for (int t = 0; t < 8; ++t) {
      z[t] = fmaf(acc[t][j], invp, xH[(size_t)node * 128 + t * 16 + col]);
      s2z = fmaf(z[t], z[t], s2z);
    }
#pragma unroll
    for (int off = 1; off < 16; off <<= 1) s2z += __shfl_xor(s2z, off, 64);
    float z0 = __shfl(z[0], gbase, 64);
    float invz = 1.f / sqrtf(fmaxf(fabsf(s2z - 2.f * z0 * z0), 1e-8f));

#pragma unroll
    for (int t = 0; t < 8; ++t)
      out[(size_t)node * 128 + t * 16 + col] = z[t] * invz;
  }
}

extern "C" void kernel_launch(void* const* d_in, const int* in_sizes, int n_in,
                              void* d_out, int out_size, void* d_ws, size_t ws_size,
                              hipStream_t stream) {
  const float* xH    = (const float*)d_in[0];
  const float* xS    = (const float*)d_in[1];
  const int*   ei    = (const int*)d_in[2];
  const float* Wq    = (const float*)d_in[3];
  const float* Wk    = (const float*)d_in[4];
  const float* Wv    = (const float*)d_in[5];
  const float* Ws    = (const float*)d_in[6];
  const float* Wproj = (const float*)d_in[7];
  float* out = (float*)d_out;

  int N = in_sizes[0] / 128;
  int E = in_sizes[2] / 2;

  char* ws = (char*)d_ws;
  size_t off = 0;
  auto alloc = [&](size_t bytes) {
    void* p = ws + off;
    off = (off + bytes + 255) & ~(size_t)255;
    return p;
  };
  float*   a      = (float*)alloc((size_t)N * 4);
  float*   b      = (float*)alloc((size_t)N * 4);
  float*   v      = (float*)alloc((size_t)N * 64 * 4);
  float*   om     = (float*)alloc((size_t)N * 64 * 4);
  EdgeRec* csr    = (EdgeRec*)alloc((size_t)E * 8);
  int*     deg    = (int*)alloc((size_t)N * 4);
  int*     cursor = (int*)alloc((size_t)N * 4);
  int*     rowptr = (int*)alloc((size_t)(N + 1) * 4);
  int*     bsum   = (int*)alloc(64 * 4);
  u16*     Whi    = (u16*)alloc((size_t)192 * 128 * 2);
  u16*     Wlo    = (u16*)alloc((size_t)192 * 128 * 2);
  u16*     Wphi   = (u16*)alloc((size_t)128 * 64 * 2);
  u16*     Wplo   = (u16*)alloc((size_t)128 * 64 * 2);

  int nb = (N + 1023) / 1024;   // 49 <= 64

  k_init<<<(N + 255) / 256, 256, 0, stream>>>(deg, cursor, N);

  k_wprep<<<(192 * 128 + 255) / 256, 256, 0, stream>>>(Wq, Wk, Wv, Whi, Wlo);
  k_wprep_p<<<(128 * 64 + 255) / 256, 256, 0, stream>>>(Wproj, Wphi, Wplo);

  int n_tiles = (N + 63) / 64;
  k_lin_mfma<<<n_tiles, 256, 0, stream>>>(xH, xS, Whi, Wlo, Ws, a, b, v, N);

  k_deg<<<(E + 255) / 256, 256, 0, stream>>>(ei, deg, E);

  k_scan1<<<nb, 1024, 0, stream>>>(deg, bsum, N);
  k_scan2<<<1, 64, 0, stream>>>(bsum, nb);
  k_scan3<<<nb, 1024, 0, stream>>>(deg, bsum, rowptr, N);

  k_csr<<<(E + 255) / 256, 256, 0, stream>>>(ei, a, b, rowptr, cursor, csr, E);

  k_agg1<<<(N + 3) / 4, 256, 0, stream>>>(rowptr, csr, v, om, N);

  k_proj_mfma<<<n_tiles, 256, 0, stream>>>(om, Wphi, Wplo, xH, out, N);
}

// Round 6
// 203.744 us; speedup vs baseline: 3.3079x; 1.0451x over previous
//
#include <hip/hip_runtime.h>
#include <math.h>

typedef __attribute__((ext_vector_type(8))) __bf16 bf16x8;
typedef __attribute__((ext_vector_type(4))) float f32x4;
typedef unsigned short u16;

struct __align__(8) EdgeRec { int d; float s; };

// Fused: zero deg/cursor + W-prep (Wcat 192x128 and Wproj 128x64 -> hi/lo bf16 planes)
__global__ void k_prep(int* __restrict__ deg, int* __restrict__ cursor, int n,
                       const float* __restrict__ Wq, const float* __restrict__ Wk,
                       const float* __restrict__ Wv, const float* __restrict__ Wp,
                       u16* __restrict__ Whi, u16* __restrict__ Wlo,
                       u16* __restrict__ Wphi, u16* __restrict__ Wplo) {
  int i = blockIdx.x * blockDim.x + threadIdx.x;
  if (i < n) { deg[i] = 0; cursor[i] = 0; }
  if (i < 192 * 128) {
    int r = i >> 7, c = i & 127;
    float x = (r < 64) ? Wq[r * 128 + c] : (r < 128) ? Wk[(r - 64) * 128 + c]
                                                     : Wv[(r - 128) * 128 + c];
    unsigned u = __float_as_uint(x);
    float lo = x - __uint_as_float(u & 0xffff0000u);
    Whi[i] = (u16)(u >> 16);
    Wlo[i] = (u16)(__float_as_uint(lo) >> 16);
  }
  if (i < 128 * 64) {
    float x = Wp[i];
    unsigned u = __float_as_uint(x);
    float lo = x - __uint_as_float(u & 0xffff0000u);
    Wphi[i] = (u16)(u >> 16);
    Wplo[i] = (u16)(__float_as_uint(lo) >> 16);
  }
}

__device__ __forceinline__ void packhl(float4 f0, float4 f1, bf16x8* ph, bf16x8* pl) {
  float xv[8] = {f0.x, f0.y, f0.z, f0.w, f1.x, f1.y, f1.z, f1.w};
  union { u16 u[8]; bf16x8 v; } H, L;
#pragma unroll
  for (int e = 0; e < 8; ++e) {
    unsigned u = __float_as_uint(xv[e]);
    float lo = xv[e] - __uint_as_float(u & 0xffff0000u);
    H.u[e] = (u16)(u >> 16);
    L.u[e] = (u16)(__float_as_uint(lo) >> 16);
  }
  *ph = H.v; *pl = L.v;
}

// MFMA linear: C[64 nodes x 192 outs] per block (4 waves, 16 rows each).
// cols 0..63=q (A from xS), 64..127=k, 128..191=v (A from xH).
// Split-bf16: C = Ah*Bh + Al*Bh + Ah*Bl.
// v2: pre-pack A for all k-steps; stage all 24 B-frags per k-step in regs.
__global__ __launch_bounds__(256, 2) void k_lin_mfma(
    const float* __restrict__ xH, const float* __restrict__ xS,
    const u16* __restrict__ Whi, const u16* __restrict__ Wlo,
    const float* __restrict__ Ws, float* __restrict__ a, float* __restrict__ b,
    float* __restrict__ v, int n_nodes) {
  int w = threadIdx.x >> 6;
  int lane = threadIdx.x & 63;
  int col = lane & 15;   // A-row / B-col within tile
  int kg = lane >> 4;    // k-group (8 elems each)
  int n0w = blockIdx.x * 64 + w * 16;
  int arow = n0w + col; if (arow >= n_nodes) arow = n_nodes - 1;

  const float* xh = xH + (size_t)arow * 128;
  const float* xs = xS + (size_t)arow * 128;

  // pre-pack A fragments for all 4 k-steps
  bf16x8 aSh[4], aSl[4], aHh[4], aHl[4];
#pragma unroll
  for (int ks = 0; ks < 4; ++ks) {
    int ko = ks * 32 + kg * 8;
    packhl(*(const float4*)(xs + ko), *(const float4*)(xs + ko + 4), &aSh[ks], &aSl[ks]);
    packhl(*(const float4*)(xh + ko), *(const float4*)(xh + ko + 4), &aHh[ks], &aHl[ks]);
  }

  f32x4 acc[12];
#pragma unroll
  for (int t = 0; t < 12; ++t) acc[t] = (f32x4){0.f, 0.f, 0.f, 0.f};

#pragma unroll
  for (int ks = 0; ks < 4; ++ks) {
    int ko = ks * 32 + kg * 8;
    bf16x8 bh[12], bl[12];
#pragma unroll
    for (int t = 0; t < 12; ++t) {            // 24 independent loads, no use in between
      size_t woff = (size_t)(16 * t + col) * 128 + ko;
      bh[t] = *(const bf16x8*)(Whi + woff);
      bl[t] = *(const bf16x8*)(Wlo + woff);
    }
#pragma unroll
    for (int t = 0; t < 12; ++t) {            // 36 back-to-back MFMAs
      bf16x8 ah = (t < 4) ? aSh[ks] : aHh[ks];
      bf16x8 al = (t < 4) ? aSl[ks] : aHl[ks];
      acc[t] = __builtin_amdgcn_mfma_f32_16x16x32_bf16(ah, bh[t], acc[t], 0, 0, 0);
      acc[t] = __builtin_amdgcn_mfma_f32_16x16x32_bf16(al, bh[t], acc[t], 0, 0, 0);
      acc[t] = __builtin_amdgcn_mfma_f32_16x16x32_bf16(ah, bl[t], acc[t], 0, 0, 0);
    }
  }

  // epilogue: row r = kg*4 + j held at reg j, col = lane&15 per tile
  float wsq[4], wsk[4];
#pragma unroll
  for (int t = 0; t < 4; ++t) { wsq[t] = Ws[16 * t + col]; wsk[t] = Ws[64 + 16 * t + col]; }

#pragma unroll
  for (int j = 0; j < 4; ++j) {
    float q2 = 0.f, k2 = 0.f, v2 = 0.f, aj = 0.f, bj = 0.f;
#pragma unroll
    for (int t = 0; t < 4; ++t) {
      float cq = acc[t][j];     q2 = fmaf(cq, cq, q2); aj = fmaf(cq, wsq[t], aj);
      float ck = acc[t + 4][j]; k2 = fmaf(ck, ck, k2); bj = fmaf(ck, wsk[t], bj);
      float cv = acc[t + 8][j]; v2 = fmaf(cv, cv, v2);
    }
#pragma unroll
    for (int off = 1; off < 16; off <<= 1) {
      q2 += __shfl_xor(q2, off, 64);
      k2 += __shfl_xor(k2, off, 64);
      v2 += __shfl_xor(v2, off, 64);
      aj += __shfl_xor(aj, off, 64);
      bj += __shfl_xor(bj, off, 64);
    }
    int gbase = lane & 48;
    float q0 = __shfl(acc[0][j], gbase, 64);
    float k0 = __shfl(acc[4][j], gbase, 64);
    float v0 = __shfl(acc[8][j], gbase, 64);
    float invq = 1.f / sqrtf(fmaxf(fabsf(q2 - 2.f * q0 * q0), 1e-8f));
    float invk = 1.f / sqrtf(fmaxf(fabsf(k2 - 2.f * k0 * k0), 1e-8f));
    float invv = 1.f / sqrtf(fmaxf(fabsf(v2 - 2.f * v0 * v0), 1e-8f));
    int node = n0w + kg * 4 + j; if (node >= n_nodes) node = n_nodes - 1;
    if (col == 0) { a[node] = aj * invq; b[node] = bj * invk; }
#pragma unroll
    for (int t = 0; t < 4; ++t)
      v[(size_t)node * 64 + t * 16 + col] = acc[t + 8][j] * invv;
  }
}

__global__ void k_deg(const int* __restrict__ ei, int* __restrict__ deg, int n_edges) {
  int e = blockIdx.x * blockDim.x + threadIdx.x;
  if (e < n_edges) atomicAdd(deg + ei[e], 1);
}

// ---- 3-phase block scan: deg -> rowptr (exclusive) ----
__global__ __launch_bounds__(1024) void k_scan1(const int* __restrict__ deg,
                                                int* __restrict__ bsum, int n) {
  __shared__ int ws[16];
  int i = blockIdx.x * 1024 + threadIdx.x;
  int x = (i < n) ? deg[i] : 0;
  int s = x;
#pragma unroll
  for (int off = 1; off < 64; off <<= 1) s += __shfl_xor(s, off, 64);
  if ((threadIdx.x & 63) == 0) ws[threadIdx.x >> 6] = s;
  __syncthreads();
  if (threadIdx.x == 0) {
    int t = 0;
#pragma unroll
    for (int k = 0; k < 16; ++k) t += ws[k];
    bsum[blockIdx.x] = t;
  }
}

__global__ void k_scan2(int* __restrict__ bsum, int nb) {  // 1 wave, nb<=64
  int lane = threadIdx.x;
  int orig = (lane < nb) ? bsum[lane] : 0;
  int x = orig;
#pragma unroll
  for (int off = 1; off < 64; off <<= 1) {
    int y = __shfl_up(x, off, 64);
    if (lane >= off) x += y;
  }
  if (lane < nb) bsum[lane] = x - orig;  // exclusive
}

__global__ __launch_bounds__(1024) void k_scan3(const int* __restrict__ deg,
                                                const int* __restrict__ bsum,
                                                int* __restrict__ rowptr, int n) {
  __shared__ int ws[16];
  __shared__ int woff[16];
  int i = blockIdx.x * 1024 + threadIdx.x;
  int lane = threadIdx.x & 63, w = threadIdx.x >> 6;
  int x = (i < n) ? deg[i] : 0;
  int inc = x;
#pragma unroll
  for (int off = 1; off < 64; off <<= 1) {
    int y = __shfl_up(inc, off, 64);
    if (lane >= off) inc += y;
  }
  if (lane == 63) ws[w] = inc;
  __syncthreads();
  if (threadIdx.x == 0) {
    int t = 0;
#pragma unroll
    for (int k = 0; k < 16; ++k) { woff[k] = t; t += ws[k]; }
  }
  __syncthreads();
  int excl = inc - x + woff[w] + bsum[blockIdx.x];
  if (i < n) rowptr[i] = excl;
  if (i == n - 1) rowptr[n] = excl + x;
}

// score + CSR scatter fused; packed 8B records
__global__ void k_csr(const int* __restrict__ ei, const float* __restrict__ a,
                      const float* __restrict__ b, const int* __restrict__ rowptr,
                      int* __restrict__ cursor, EdgeRec* __restrict__ csr, int n_edges) {
  int e = blockIdx.x * blockDim.x + threadIdx.x;
  if (e >= n_edges) return;
  int src = ei[e];
  int dst = ei[n_edges + e];
  float s = a[src] + b[dst];
  float sc = s > 0.f ? s : 0.01f * s;   // LeakyReLU(0.01)
  int slot = atomicAdd(cursor + src, 1);
  EdgeRec er; er.d = dst; er.s = sc;
  csr[rowptr[src] + slot] = er;
}

// Wave per node: coalesced csr prefetch -> unrolled independent v gathers.
// Writes om[n][64] = to_manifold(origin + softmax-agg of v).
__global__ __launch_bounds__(256) void k_agg1(
    const int* __restrict__ rowptr, const EdgeRec* __restrict__ csr,
    const float* __restrict__ v, float* __restrict__ om, int n_nodes) {
  int wib = threadIdx.x >> 6;
  int lane = threadIdx.x & 63;
  int n = blockIdx.x * 4 + wib;
  if (n >= n_nodes) return;            // wave-uniform

  int r0 = rowptr[n], r1 = rowptr[n + 1];
  int g = lane >> 4, l16 = lane & 15;
  float4 acc = make_float4(0.f, 0.f, 0.f, 0.f);
  float ssl = 0.f;                     // per-lane exp sum

  for (int base = r0; base < r1; base += 64) {
    int cnt = r1 - base; if (cnt > 64) cnt = 64;
    int erd = 0; float wl = 0.f;
    if (lane < cnt) {
      EdgeRec er = csr[base + lane];   // one coalesced 512B load
      erd = er.d;
      wl = __expf(er.s);
    }
    ssl += wl;
#pragma unroll
    for (int j = 0; j < 16; ++j) {
      int idx = g + 4 * j;             // uniform within 16-lane group
      int d = __shfl(erd, idx, 64);
      float w = __shfl(wl, idx, 64);
      if (idx < cnt) {
        float4 vv = ((const float4*)(v + (size_t)d * 64))[l16];
        acc.x = fmaf(w, vv.x, acc.x);
        acc.y = fmaf(w, vv.y, acc.y);
        acc.z = fmaf(w, vv.z, acc.z);
        acc.w = fmaf(w, vv.w, acc.w);
      }
    }
  }

  // reduce 4 groups + exp-sum across wave
#pragma unroll
  for (int off = 16; off < 64; off <<= 1) {
    acc.x += __shfl_xor(acc.x, off, 64);
    acc.y += __shfl_xor(acc.y, off, 64);
    acc.z += __shfl_xor(acc.z, off, 64);
    acc.w += __shfl_xor(acc.w, off, 64);
  }
#pragma unroll
  for (int off = 1; off < 64; off <<= 1) ssl += __shfl_xor(ssl, off, 64);

  if (r1 > r0) {
    float is = 1.f / ssl;
    acc.x *= is; acc.y *= is; acc.z *= is; acc.w *= is;
  }
  if (l16 == 0) acc.x += 1.0f;         // origin (dim 0)

  float s2 = acc.x * acc.x + acc.y * acc.y + acc.z * acc.z + acc.w * acc.w;
#pragma unroll
  for (int off = 1; off < 16; off <<= 1) s2 += __shfl_xor(s2, off, 64);
  float o0 = __shfl(acc.x, 0, 64);
  float inner = s2 - 2.f * o0 * o0;
  float sc = 1.f / sqrtf(fmaxf(fabsf(inner), 1e-8f));
  if (g == 0)
    ((float4*)(om + (size_t)n * 64))[l16] =
        make_float4(acc.x * sc, acc.y * sc, acc.z * sc, acc.w * sc);
}

// MFMA projection: C[64 nodes x 128 outs] per block (4 waves, 16 rows each).
// p = om@Wproj^T, x = norm_L(p), z = norm_L(x + xH) -> out.
// v2: B-frag register staging per k-step.
__global__ __launch_bounds__(256, 3) void k_proj_mfma(
    const float* __restrict__ om, const u16* __restrict__ Whi,
    const u16* __restrict__ Wlo, const float* __restrict__ xH,
    float* __restrict__ out, int n_nodes) {
  int w = threadIdx.x >> 6;
  int lane = threadIdx.x & 63;
  int col = lane & 15;
  int kg = lane >> 4;
  int n0w = blockIdx.x * 64 + w * 16;
  int arow = n0w + col; if (arow >= n_nodes) arow = n_nodes - 1;

  const float* orow = om + (size_t)arow * 64;

  bf16x8 ah[2], al[2];
#pragma unroll
  for (int ks = 0; ks < 2; ++ks) {
    int ko = ks * 32 + kg * 8;
    packhl(*(const float4*)(orow + ko), *(const float4*)(orow + ko + 4), &ah[ks], &al[ks]);
  }

  f32x4 acc[8];
#pragma unroll
  for (int t = 0; t < 8; ++t) acc[t] = (f32x4){0.f, 0.f, 0.f, 0.f};

#pragma unroll
  for (int ks = 0; ks < 2; ++ks) {
    int ko = ks * 32 + kg * 8;
    bf16x8 bh[8], bl[8];
#pragma unroll
    for (int t = 0; t < 8; ++t) {
      size_t woff = (size_t)(16 * t + col) * 64 + ko;
      bh[t] = *(const bf16x8*)(Whi + woff);
      bl[t] = *(const bf16x8*)(Wlo + woff);
    }
#pragma unroll
    for (int t = 0; t < 8; ++t) {
      acc[t] = __builtin_amdgcn_mfma_f32_16x16x32_bf16(ah[ks], bh[t], acc[t], 0, 0, 0);
      acc[t] = __builtin_amdgcn_mfma_f32_16x16x32_bf16(al[ks], bh[t], acc[t], 0, 0, 0);
      acc[t] = __builtin_amdgcn_mfma_f32_16x16x32_bf16(ah[ks], bl[t], acc[t], 0, 0, 0);
    }
  }

  int gbase = lane & 48;
#pragma unroll
  for (int j = 0; j < 4; ++j) {
    int node = n0w + kg * 4 + j; if (node >= n_nodes) node = n_nodes - 1;

    float s2p = 0.f;
#pragma unroll
    for (int t = 0; t < 8; ++t) s2p = fmaf(acc[t][j], acc[t][j], s2p);
#pragma unroll
    for (int off = 1; off < 16; off <<= 1) s2p += __shfl_xor(s2p, off, 64);
    float p0 = __shfl(acc[0][j], gbase, 64);
    float invp = 1.f / sqrtf(fmaxf(fabsf(s2p - 2.f * p0 * p0), 1e-8f));

    float z[8];
    float s2z = 0.f;
#pragma unroll
    for (int t = 0; t < 8; ++t) {
      z[t] = fmaf(acc[t][j], invp, xH[(size_t)node * 128 + t * 16 + col]);
      s2z = fmaf(z[t], z[t], s2z);
    }
#pragma unroll
    for (int off = 1; off < 16; off <<= 1) s2z += __shfl_xor(s2z, off, 64);
    float z0 = __shfl(z[0], gbase, 64);
    float invz = 1.f / sqrtf(fmaxf(fabsf(s2z - 2.f * z0 * z0), 1e-8f));

#pragma unroll
    for (int t = 0; t < 8; ++t)
      out[(size_t)node * 128 + t * 16 + col] = z[t] * invz;
  }
}

extern "C" void kernel_launch(void* const* d_in, const int* in_sizes, int n_in,
                              void* d_out, int out_size, void* d_ws, size_t ws_size,
                              hipStream_t stream) {
  const float* xH    = (const float*)d_in[0];
  const float* xS    = (const float*)d_in[1];
  const int*   ei    = (const int*)d_in[2];
  const float* Wq    = (const float*)d_in[3];
  const float* Wk    = (const float*)d_in[4];
  const float* Wv    = (const float*)d_in[5];
  const float* Ws    = (const float*)d_in[6];
  const float* Wproj = (const float*)d_in[7];
  float* out = (float*)d_out;

  int N = in_sizes[0] / 128;
  int E = in_sizes[2] / 2;

  char* ws = (char*)d_ws;
  size_t off = 0;
  auto alloc = [&](size_t bytes) {
    void* p = ws + off;
    off = (off + bytes + 255) & ~(size_t)255;
    return p;
  };
  float*   a      = (float*)alloc((size_t)N * 4);
  float*   b      = (float*)alloc((size_t)N * 4);
  float*   v      = (float*)alloc((size_t)N * 64 * 4);
  float*   om     = (float*)alloc((size_t)N * 64 * 4);
  EdgeRec* csr    = (EdgeRec*)alloc((size_t)E * 8);
  int*     deg    = (int*)alloc((size_t)N * 4);
  int*     cursor = (int*)alloc((size_t)N * 4);
  int*     rowptr = (int*)alloc((size_t)(N + 1) * 4);
  int*     bsum   = (int*)alloc(64 * 4);
  u16*     Whi    = (u16*)alloc((size_t)192 * 128 * 2);
  u16*     Wlo    = (u16*)alloc((size_t)192 * 128 * 2);
  u16*     Wphi   = (u16*)alloc((size_t)128 * 64 * 2);
  u16*     Wplo   = (u16*)alloc((size_t)128 * 64 * 2);

  int nb = (N + 1023) / 1024;   // 49 <= 64

  k_prep<<<(N + 255) / 256, 256, 0, stream>>>(deg, cursor, N, Wq, Wk, Wv, Wproj,
                                              Whi, Wlo, Wphi, Wplo);

  int n_tiles = (N + 63) / 64;
  k_lin_mfma<<<n_tiles, 256, 0, stream>>>(xH, xS, Whi, Wlo, Ws, a, b, v, N);

  k_deg<<<(E + 255) / 256, 256, 0, stream>>>(ei, deg, E);

  k_scan1<<<nb, 1024, 0, stream>>>(deg, bsum, N);
  k_scan2<<<1, 64, 0, stream>>>(bsum, nb);
  k_scan3<<<nb, 1024, 0, stream>>>(deg, bsum, rowptr, N);

  k_csr<<<(E + 255) / 256, 256, 0, stream>>>(ei, a, b, rowptr, cursor, csr, E);

  k_agg1<<<(N + 3) / 4, 256, 0, stream>>>(rowptr, csr, v, om, N);

  k_proj_mfma<<<n_tiles, 256, 0, stream>>>(om, Wphi, Wplo, xH, out, N);
}

// Round 7
// 199.474 us; speedup vs baseline: 3.3787x; 1.0214x over previous
//
#include <hip/hip_runtime.h>
#include <math.h>

typedef __attribute__((ext_vector_type(8))) __bf16 bf16x8;
typedef __attribute__((ext_vector_type(4))) float f32x4;
typedef unsigned short u16;

struct __align__(8) EdgeRec { int d; float s; };

// Fused: zero deg/cursor + W-prep (Wcat 192x128 and Wproj 128x64 -> hi/lo bf16 planes)
__global__ void k_prep(int* __restrict__ deg, int* __restrict__ cursor, int n,
                       const float* __restrict__ Wq, const float* __restrict__ Wk,
                       const float* __restrict__ Wv, const float* __restrict__ Wp,
                       u16* __restrict__ Whi, u16* __restrict__ Wlo,
                       u16* __restrict__ Wphi, u16* __restrict__ Wplo) {
  int i = blockIdx.x * blockDim.x + threadIdx.x;
  if (i < n) { deg[i] = 0; cursor[i] = 0; }
  if (i < 192 * 128) {
    int r = i >> 7, c = i & 127;
    float x = (r < 64) ? Wq[r * 128 + c] : (r < 128) ? Wk[(r - 64) * 128 + c]
                                                     : Wv[(r - 128) * 128 + c];
    unsigned u = __float_as_uint(x);
    float lo = x - __uint_as_float(u & 0xffff0000u);
    Whi[i] = (u16)(u >> 16);
    Wlo[i] = (u16)(__float_as_uint(lo) >> 16);
  }
  if (i < 128 * 64) {
    float x = Wp[i];
    unsigned u = __float_as_uint(x);
    float lo = x - __uint_as_float(u & 0xffff0000u);
    Wphi[i] = (u16)(u >> 16);
    Wplo[i] = (u16)(__float_as_uint(lo) >> 16);
  }
}

__device__ __forceinline__ void packhl(float4 f0, float4 f1, bf16x8* ph, bf16x8* pl) {
  float xv[8] = {f0.x, f0.y, f0.z, f0.w, f1.x, f1.y, f1.z, f1.w};
  union { u16 u[8]; bf16x8 v; } H, L;
#pragma unroll
  for (int e = 0; e < 8; ++e) {
    unsigned u = __float_as_uint(xv[e]);
    float lo = xv[e] - __uint_as_float(u & 0xffff0000u);
    H.u[e] = (u16)(u >> 16);
    L.u[e] = (u16)(__float_as_uint(lo) >> 16);
  }
  *ph = H.v; *pl = L.v;
}

// MFMA linear, 1-wave blocks: C[16 nodes x 192 outs] per wave.
// cols 0..63=q (A from xS), 64..127=k, 128..191=v (A from xH).
// Split-bf16: C = Ah*Bh + Al*Bh + Ah*Bl.
__global__ __launch_bounds__(64) void k_lin_mfma(
    const float* __restrict__ xH, const float* __restrict__ xS,
    const u16* __restrict__ Whi, const u16* __restrict__ Wlo,
    const float* __restrict__ Ws, float* __restrict__ a, float* __restrict__ b,
    float* __restrict__ v, int n_nodes) {
  int lane = threadIdx.x;
  int col = lane & 15;   // A-row / B-col within tile
  int kg = lane >> 4;    // k-group (8 elems each)
  int n0w = blockIdx.x * 16;
  int arow = n0w + col; if (arow >= n_nodes) arow = n_nodes - 1;

  const float* xh = xH + (size_t)arow * 128;
  const float* xs = xS + (size_t)arow * 128;

  // pre-pack A fragments for all 4 k-steps
  bf16x8 aSh[4], aSl[4], aHh[4], aHl[4];
#pragma unroll
  for (int ks = 0; ks < 4; ++ks) {
    int ko = ks * 32 + kg * 8;
    packhl(*(const float4*)(xs + ko), *(const float4*)(xs + ko + 4), &aSh[ks], &aSl[ks]);
    packhl(*(const float4*)(xh + ko), *(const float4*)(xh + ko + 4), &aHh[ks], &aHl[ks]);
  }

  f32x4 acc[12];
#pragma unroll
  for (int t = 0; t < 12; ++t) acc[t] = (f32x4){0.f, 0.f, 0.f, 0.f};

#pragma unroll
  for (int ks = 0; ks < 4; ++ks) {
    int ko = ks * 32 + kg * 8;
    bf16x8 bh[12], bl[12];
#pragma unroll
    for (int t = 0; t < 12; ++t) {
      size_t woff = (size_t)(16 * t + col) * 128 + ko;
      bh[t] = *(const bf16x8*)(Whi + woff);
      bl[t] = *(const bf16x8*)(Wlo + woff);
    }
#pragma unroll
    for (int t = 0; t < 12; ++t) {
      bf16x8 ah = (t < 4) ? aSh[ks] : aHh[ks];
      bf16x8 al = (t < 4) ? aSl[ks] : aHl[ks];
      acc[t] = __builtin_amdgcn_mfma_f32_16x16x32_bf16(ah, bh[t], acc[t], 0, 0, 0);
      acc[t] = __builtin_amdgcn_mfma_f32_16x16x32_bf16(al, bh[t], acc[t], 0, 0, 0);
      acc[t] = __builtin_amdgcn_mfma_f32_16x16x32_bf16(ah, bl[t], acc[t], 0, 0, 0);
    }
  }

  // epilogue: row r = kg*4 + j held at reg j, col = lane&15 per tile
  float wsq[4], wsk[4];
#pragma unroll
  for (int t = 0; t < 4; ++t) { wsq[t] = Ws[16 * t + col]; wsk[t] = Ws[64 + 16 * t + col]; }

#pragma unroll
  for (int j = 0; j < 4; ++j) {
    float q2 = 0.f, k2 = 0.f, v2 = 0.f, aj = 0.f, bj = 0.f;
#pragma unroll
    for (int t = 0; t < 4; ++t) {
      float cq = acc[t][j];     q2 = fmaf(cq, cq, q2); aj = fmaf(cq, wsq[t], aj);
      float ck = acc[t + 4][j]; k2 = fmaf(ck, ck, k2); bj = fmaf(ck, wsk[t], bj);
      float cv = acc[t + 8][j]; v2 = fmaf(cv, cv, v2);
    }
#pragma unroll
    for (int off = 1; off < 16; off <<= 1) {
      q2 += __shfl_xor(q2, off, 64);
      k2 += __shfl_xor(k2, off, 64);
      v2 += __shfl_xor(v2, off, 64);
      aj += __shfl_xor(aj, off, 64);
      bj += __shfl_xor(bj, off, 64);
    }
    int gbase = lane & 48;
    float q0 = __shfl(acc[0][j], gbase, 64);
    float k0 = __shfl(acc[4][j], gbase, 64);
    float v0 = __shfl(acc[8][j], gbase, 64);
    float invq = 1.f / sqrtf(fmaxf(fabsf(q2 - 2.f * q0 * q0), 1e-8f));
    float invk = 1.f / sqrtf(fmaxf(fabsf(k2 - 2.f * k0 * k0), 1e-8f));
    float invv = 1.f / sqrtf(fmaxf(fabsf(v2 - 2.f * v0 * v0), 1e-8f));
    int node = n0w + kg * 4 + j; if (node >= n_nodes) node = n_nodes - 1;
    if (col == 0) { a[node] = aj * invq; b[node] = bj * invk; }
#pragma unroll
    for (int t = 0; t < 4; ++t)
      v[(size_t)node * 64 + t * 16 + col] = acc[t + 8][j] * invv;
  }
}

__global__ void k_deg(const int* __restrict__ ei, int* __restrict__ deg, int n_edges) {
  int e = blockIdx.x * blockDim.x + threadIdx.x;
  if (e < n_edges) atomicAdd(deg + ei[e], 1);
}

// ---- 3-phase block scan: deg -> rowptr (exclusive) ----
__global__ __launch_bounds__(1024) void k_scan1(const int* __restrict__ deg,
                                                int* __restrict__ bsum, int n) {
  __shared__ int ws[16];
  int i = blockIdx.x * 1024 + threadIdx.x;
  int x = (i < n) ? deg[i] : 0;
  int s = x;
#pragma unroll
  for (int off = 1; off < 64; off <<= 1) s += __shfl_xor(s, off, 64);
  if ((threadIdx.x & 63) == 0) ws[threadIdx.x >> 6] = s;
  __syncthreads();
  if (threadIdx.x == 0) {
    int t = 0;
#pragma unroll
    for (int k = 0; k < 16; ++k) t += ws[k];
    bsum[blockIdx.x] = t;
  }
}

__global__ void k_scan2(int* __restrict__ bsum, int nb) {  // 1 wave, nb<=64
  int lane = threadIdx.x;
  int orig = (lane < nb) ? bsum[lane] : 0;
  int x = orig;
#pragma unroll
  for (int off = 1; off < 64; off <<= 1) {
    int y = __shfl_up(x, off, 64);
    if (lane >= off) x += y;
  }
  if (lane < nb) bsum[lane] = x - orig;  // exclusive
}

__global__ __launch_bounds__(1024) void k_scan3(const int* __restrict__ deg,
                                                const int* __restrict__ bsum,
                                                int* __restrict__ rowptr, int n) {
  __shared__ int ws[16];
  __shared__ int woff[16];
  int i = blockIdx.x * 1024 + threadIdx.x;
  int lane = threadIdx.x & 63, w = threadIdx.x >> 6;
  int x = (i < n) ? deg[i] : 0;
  int inc = x;
#pragma unroll
  for (int off = 1; off < 64; off <<= 1) {
    int y = __shfl_up(inc, off, 64);
    if (lane >= off) inc += y;
  }
  if (lane == 63) ws[w] = inc;
  __syncthreads();
  if (threadIdx.x == 0) {
    int t = 0;
#pragma unroll
    for (int k = 0; k < 16; ++k) { woff[k] = t; t += ws[k]; }
  }
  __syncthreads();
  int excl = inc - x + woff[w] + bsum[blockIdx.x];
  if (i < n) rowptr[i] = excl;
  if (i == n - 1) rowptr[n] = excl + x;
}

// score + CSR scatter fused; packed 8B records
__global__ void k_csr(const int* __restrict__ ei, const float* __restrict__ a,
                      const float* __restrict__ b, const int* __restrict__ rowptr,
                      int* __restrict__ cursor, EdgeRec* __restrict__ csr, int n_edges) {
  int e = blockIdx.x * blockDim.x + threadIdx.x;
  if (e >= n_edges) return;
  int src = ei[e];
  int dst = ei[n_edges + e];
  float s = a[src] + b[dst];
  float sc = s > 0.f ? s : 0.01f * s;   // LeakyReLU(0.01)
  int slot = atomicAdd(cursor + src, 1);
  EdgeRec er; er.d = dst; er.s = sc;
  csr[rowptr[src] + slot] = er;
}

// Wave per node: coalesced csr prefetch -> unrolled independent v gathers.
// Writes om[n][64] = to_manifold(origin + softmax-agg of v).
__global__ __launch_bounds__(256) void k_agg1(
    const int* __restrict__ rowptr, const EdgeRec* __restrict__ csr,
    const float* __restrict__ v, float* __restrict__ om, int n_nodes) {
  int wib = threadIdx.x >> 6;
  int lane = threadIdx.x & 63;
  int n = blockIdx.x * 4 + wib;
  if (n >= n_nodes) return;            // wave-uniform

  int r0 = rowptr[n], r1 = rowptr[n + 1];
  int g = lane >> 4, l16 = lane & 15;
  float4 acc = make_float4(0.f, 0.f, 0.f, 0.f);
  float ssl = 0.f;                     // per-lane exp sum

  for (int base = r0; base < r1; base += 64) {
    int cnt = r1 - base; if (cnt > 64) cnt = 64;
    int erd = 0; float wl = 0.f;
    if (lane < cnt) {
      EdgeRec er = csr[base + lane];   // one coalesced 512B load
      erd = er.d;
      wl = __expf(er.s);
    }
    ssl += wl;
#pragma unroll
    for (int j = 0; j < 16; ++j) {
      int idx = g + 4 * j;             // uniform within 16-lane group
      int d = __shfl(erd, idx, 64);
      float w = __shfl(wl, idx, 64);
      if (idx < cnt) {
        float4 vv = ((const float4*)(v + (size_t)d * 64))[l16];
        acc.x = fmaf(w, vv.x, acc.x);
        acc.y = fmaf(w, vv.y, acc.y);
        acc.z = fmaf(w, vv.z, acc.z);
        acc.w = fmaf(w, vv.w, acc.w);
      }
    }
  }

  // reduce 4 groups + exp-sum across wave
#pragma unroll
  for (int off = 16; off < 64; off <<= 1) {
    acc.x += __shfl_xor(acc.x, off, 64);
    acc.y += __shfl_xor(acc.y, off, 64);
    acc.z += __shfl_xor(acc.z, off, 64);
    acc.w += __shfl_xor(acc.w, off, 64);
  }
#pragma unroll
  for (int off = 1; off < 64; off <<= 1) ssl += __shfl_xor(ssl, off, 64);

  if (r1 > r0) {
    float is = 1.f / ssl;
    acc.x *= is; acc.y *= is; acc.z *= is; acc.w *= is;
  }
  if (l16 == 0) acc.x += 1.0f;         // origin (dim 0)

  float s2 = acc.x * acc.x + acc.y * acc.y + acc.z * acc.z + acc.w * acc.w;
#pragma unroll
  for (int off = 1; off < 16; off <<= 1) s2 += __shfl_xor(s2, off, 64);
  float o0 = __shfl(acc.x, 0, 64);
  float inner = s2 - 2.f * o0 * o0;
  float sc = 1.f / sqrtf(fmaxf(fabsf(inner), 1e-8f));
  if (g == 0)
    ((float4*)(om + (size_t)n * 64))[l16] =
        make_float4(acc.x * sc, acc.y * sc, acc.z * sc, acc.w * sc);
}

// MFMA projection, 1-wave blocks: C[16 nodes x 128 outs] per wave.
// p = om@Wproj^T, x = norm_L(p), z = norm_L(x + xH) -> out.
__global__ __launch_bounds__(64) void k_proj_mfma(
    const float* __restrict__ om, const u16* __restrict__ Whi,
    const u16* __restrict__ Wlo, const float* __restrict__ xH,
    float* __restrict__ out, int n_nodes) {
  int lane = threadIdx.x;
  int col = lane & 15;
  int kg = lane >> 4;
  int n0w = blockIdx.x * 16;
  int arow = n0w + col; if (arow >= n_nodes) arow = n_nodes - 1;

  const float* orow = om + (size_t)arow * 64;

  bf16x8 ah[2], al[2];
#pragma unroll
  for (int ks = 0; ks < 2; ++ks) {
    int ko = ks * 32 + kg * 8;
    packhl(*(const float4*)(orow + ko), *(const float4*)(orow + ko + 4), &ah[ks], &al[ks]);
  }

  f32x4 acc[8];
#pragma unroll
  for (int t = 0; t < 8; ++t) acc[t] = (f32x4){0.f, 0.f, 0.f, 0.f};

#pragma unroll
  for (int ks = 0; ks < 2; ++ks) {
    int ko = ks * 32 + kg * 8;
    bf16x8 bh[8], bl[8];
#pragma unroll
    for (int t = 0; t < 8; ++t) {
      size_t woff = (size_t)(16 * t + col) * 64 + ko;
      bh[t] = *(const bf16x8*)(Whi + woff);
      bl[t] = *(const bf16x8*)(Wlo + woff);
    }
#pragma unroll
    for (int t = 0; t < 8; ++t) {
      acc[t] = __builtin_amdgcn_mfma_f32_16x16x32_bf16(ah[ks], bh[t], acc[t], 0, 0, 0);
      acc[t] = __builtin_amdgcn_mfma_f32_16x16x32_bf16(al[ks], bh[t], acc[t], 0, 0, 0);
      acc[t] = __builtin_amdgcn_mfma_f32_16x16x32_bf16(ah[ks], bl[t], acc[t], 0, 0, 0);
    }
  }

  int gbase = lane & 48;
#pragma unroll
  for (int j = 0; j < 4; ++j) {
    int node = n0w + kg * 4 + j; if (node >= n_nodes) node = n_nodes - 1;

    float s2p = 0.f;
#pragma unroll
    for (int t = 0; t < 8; ++t) s2p = fmaf(acc[t][j], acc[t][j], s2p);
#pragma unroll
    for (int off = 1; off < 16; off <<= 1) s2p += __shfl_xor(s2p, off, 64);
    float p0 = __shfl(acc[0][j], gbase, 64);
    float invp = 1.f / sqrtf(fmaxf(fabsf(s2p - 2.f * p0 * p0), 1e-8f));

    float z[8];
    float s2z = 0.f;
#pragma unroll
    for (int t = 0; t < 8; ++t) {
      z[t] = fmaf(acc[t][j], invp, xH[(size_t)node * 128 + t * 16 + col]);
      s2z = fmaf(z[t], z[t], s2z);
    }
#pragma unroll
    for (int off = 1; off < 16; off <<= 1) s2z += __shfl_xor(s2z, off, 64);
    float z0 = __shfl(z[0], gbase, 64);
    float invz = 1.f / sqrtf(fmaxf(fabsf(s2z - 2.f * z0 * z0), 1e-8f));

#pragma unroll
    for (int t = 0; t < 8; ++t)
      out[(size_t)node * 128 + t * 16 + col] = z[t] * invz;
  }
}

extern "C" void kernel_launch(void* const* d_in, const int* in_sizes, int n_in,
                              void* d_out, int out_size, void* d_ws, size_t ws_size,
                              hipStream_t stream) {
  const float* xH    = (const float*)d_in[0];
  const float* xS    = (const float*)d_in[1];
  const int*   ei    = (const int*)d_in[2];
  const float* Wq    = (const float*)d_in[3];
  const float* Wk    = (const float*)d_in[4];
  const float* Wv    = (const float*)d_in[5];
  const float* Ws    = (const float*)d_in[6];
  const float* Wproj = (const float*)d_in[7];
  float* out = (float*)d_out;

  int N = in_sizes[0] / 128;
  int E = in_sizes[2] / 2;

  char* ws = (char*)d_ws;
  size_t off = 0;
  auto alloc = [&](size_t bytes) {
    void* p = ws + off;
    off = (off + bytes + 255) & ~(size_t)255;
    return p;
  };
  float*   a      = (float*)alloc((size_t)N * 4);
  float*   b      = (float*)alloc((size_t)N * 4);
  float*   v      = (float*)alloc((size_t)N * 64 * 4);
  float*   om     = (float*)alloc((size_t)N * 64 * 4);
  EdgeRec* csr    = (EdgeRec*)alloc((size_t)E * 8);
  int*     deg    = (int*)alloc((size_t)N * 4);
  int*     cursor = (int*)alloc((size_t)N * 4);
  int*     rowptr = (int*)alloc((size_t)(N + 1) * 4);
  int*     bsum   = (int*)alloc(64 * 4);
  u16*     Whi    = (u16*)alloc((size_t)192 * 128 * 2);
  u16*     Wlo    = (u16*)alloc((size_t)192 * 128 * 2);
  u16*     Wphi   = (u16*)alloc((size_t)128 * 64 * 2);
  u16*     Wplo   = (u16*)alloc((size_t)128 * 64 * 2);

  int nb = (N + 1023) / 1024;   // 49 <= 64

  k_prep<<<(N + 255) / 256, 256, 0, stream>>>(deg, cursor, N, Wq, Wk, Wv, Wproj,
                                              Whi, Wlo, Wphi, Wplo);

  int n_tiles16 = (N + 15) / 16;
  k_lin_mfma<<<n_tiles16, 64, 0, stream>>>(xH, xS, Whi, Wlo, Ws, a, b, v, N);

  k_deg<<<(E + 255) / 256, 256, 0, stream>>>(ei, deg, E);

  k_scan1<<<nb, 1024, 0, stream>>>(deg, bsum, N);
  k_scan2<<<1, 64, 0, stream>>>(bsum, nb);
  k_scan3<<<nb, 1024, 0, stream>>>(deg, bsum, rowptr, N);

  k_csr<<<(E + 255) / 256, 256, 0, stream>>>(ei, a, b, rowptr, cursor, csr, E);

  k_agg1<<<(N + 3) / 4, 256, 0, stream>>>(rowptr, csr, v, om, N);

  k_proj_mfma<<<n_tiles16, 64, 0, stream>>>(om, Wphi, Wplo, xH, out, N);
}

// Round 8
// 178.752 us; speedup vs baseline: 3.7703x; 1.1159x over previous
//
#include <hip/hip_runtime.h>
#include <math.h>

typedef __attribute__((ext_vector_type(8))) __bf16 bf16x8;
typedef __attribute__((ext_vector_type(4))) float f32x4;
typedef unsigned short u16;

struct __align__(8) EdgeRec { int d; float s; };

// Fused: zero deg/cursor + W-prep (Wcat 192x128 and Wproj 128x64 -> hi/lo bf16 planes)
__global__ void k_prep(int* __restrict__ deg, int* __restrict__ cursor, int n,
                       const float* __restrict__ Wq, const float* __restrict__ Wk,
                       const float* __restrict__ Wv, const float* __restrict__ Wp,
                       u16* __restrict__ Whi, u16* __restrict__ Wlo,
                       u16* __restrict__ Wphi, u16* __restrict__ Wplo) {
  int i = blockIdx.x * blockDim.x + threadIdx.x;
  if (i < n) { deg[i] = 0; cursor[i] = 0; }
  if (i < 192 * 128) {
    int r = i >> 7, c = i & 127;
    float x = (r < 64) ? Wq[r * 128 + c] : (r < 128) ? Wk[(r - 64) * 128 + c]
                                                     : Wv[(r - 128) * 128 + c];
    unsigned u = __float_as_uint(x);
    float lo = x - __uint_as_float(u & 0xffff0000u);
    Whi[i] = (u16)(u >> 16);
    Wlo[i] = (u16)(__float_as_uint(lo) >> 16);
  }
  if (i < 128 * 64) {
    float x = Wp[i];
    unsigned u = __float_as_uint(x);
    float lo = x - __uint_as_float(u & 0xffff0000u);
    Wphi[i] = (u16)(u >> 16);
    Wplo[i] = (u16)(__float_as_uint(lo) >> 16);
  }
}

__device__ __forceinline__ void packhl(float4 f0, float4 f1, bf16x8* ph, bf16x8* pl) {
  float xv[8] = {f0.x, f0.y, f0.z, f0.w, f1.x, f1.y, f1.z, f1.w};
  union { u16 u[8]; bf16x8 v; } H, L;
#pragma unroll
  for (int e = 0; e < 8; ++e) {
    unsigned u = __float_as_uint(xv[e]);
    float lo = xv[e] - __uint_as_float(u & 0xffff0000u);
    H.u[e] = (u16)(u >> 16);
    L.u[e] = (u16)(__float_as_uint(lo) >> 16);
  }
  *ph = H.v; *pl = L.v;
}

// MFMA linear with LDS-staged W. Block = 256 thr (4 waves), 64 nodes.
// Phase 1: stage Whi (48KB) -> acc += Ah*Bh + Al*Bh over all ks.
// Phase 2: stage Wlo        -> acc += Ah*Bl.
__global__ __launch_bounds__(256) void k_lin_mfma(
    const float* __restrict__ xH, const float* __restrict__ xS,
    const u16* __restrict__ Whi, const u16* __restrict__ Wlo,
    const float* __restrict__ Ws, float* __restrict__ a, float* __restrict__ b,
    float* __restrict__ v, int n_nodes) {
  __shared__ __align__(16) u16 WS[192 * 128];   // 48 KB
  int tid = threadIdx.x;
  int w = tid >> 6;
  int lane = tid & 63;
  int col = lane & 15;   // A-row / B-col within tile
  int kg = lane >> 4;    // k-group (8 elems each)
  int n0w = blockIdx.x * 64 + w * 16;
  int arow = n0w + col; if (arow >= n_nodes) arow = n_nodes - 1;

  const float* xh = xH + (size_t)arow * 128;
  const float* xs = xS + (size_t)arow * 128;

  // pre-pack A fragments for all 4 k-steps
  bf16x8 aSh[4], aSl[4], aHh[4], aHl[4];
#pragma unroll
  for (int ks = 0; ks < 4; ++ks) {
    int ko = ks * 32 + kg * 8;
    packhl(*(const float4*)(xs + ko), *(const float4*)(xs + ko + 4), &aSh[ks], &aSl[ks]);
    packhl(*(const float4*)(xh + ko), *(const float4*)(xh + ko + 4), &aHh[ks], &aHl[ks]);
  }

  // stage Whi: 48 chunks of 1KB; wave w stages chunks i*4+w
#pragma unroll
  for (int i = 0; i < 12; ++i) {
    int c = i * 4 + w;
    uint4 d = *(const uint4*)(Whi + c * 512 + lane * 8);
    *(uint4*)(WS + c * 512 + lane * 8) = d;
  }
  __syncthreads();

  f32x4 acc[12];
#pragma unroll
  for (int t = 0; t < 12; ++t) acc[t] = (f32x4){0.f, 0.f, 0.f, 0.f};

#pragma unroll
  for (int ks = 0; ks < 4; ++ks) {
#pragma unroll
    for (int t = 0; t < 12; ++t) {
      bf16x8 bh = *(const bf16x8*)(WS + (16 * t + col) * 128 + ks * 32 + kg * 8);
      bf16x8 ah = (t < 4) ? aSh[ks] : aHh[ks];
      bf16x8 al = (t < 4) ? aSl[ks] : aHl[ks];
      acc[t] = __builtin_amdgcn_mfma_f32_16x16x32_bf16(ah, bh, acc[t], 0, 0, 0);
      acc[t] = __builtin_amdgcn_mfma_f32_16x16x32_bf16(al, bh, acc[t], 0, 0, 0);
    }
  }
  __syncthreads();

  // stage Wlo
#pragma unroll
  for (int i = 0; i < 12; ++i) {
    int c = i * 4 + w;
    uint4 d = *(const uint4*)(Wlo + c * 512 + lane * 8);
    *(uint4*)(WS + c * 512 + lane * 8) = d;
  }
  __syncthreads();

#pragma unroll
  for (int ks = 0; ks < 4; ++ks) {
#pragma unroll
    for (int t = 0; t < 12; ++t) {
      bf16x8 bl = *(const bf16x8*)(WS + (16 * t + col) * 128 + ks * 32 + kg * 8);
      bf16x8 ah = (t < 4) ? aSh[ks] : aHh[ks];
      acc[t] = __builtin_amdgcn_mfma_f32_16x16x32_bf16(ah, bl, acc[t], 0, 0, 0);
    }
  }

  // epilogue: row r = kg*4 + j held at reg j, col = lane&15 per tile
  float wsq[4], wsk[4];
#pragma unroll
  for (int t = 0; t < 4; ++t) { wsq[t] = Ws[16 * t + col]; wsk[t] = Ws[64 + 16 * t + col]; }

#pragma unroll
  for (int j = 0; j < 4; ++j) {
    float q2 = 0.f, k2 = 0.f, v2 = 0.f, aj = 0.f, bj = 0.f;
#pragma unroll
    for (int t = 0; t < 4; ++t) {
      float cq = acc[t][j];     q2 = fmaf(cq, cq, q2); aj = fmaf(cq, wsq[t], aj);
      float ck = acc[t + 4][j]; k2 = fmaf(ck, ck, k2); bj = fmaf(ck, wsk[t], bj);
      float cv = acc[t + 8][j]; v2 = fmaf(cv, cv, v2);
    }
#pragma unroll
    for (int off = 1; off < 16; off <<= 1) {
      q2 += __shfl_xor(q2, off, 64);
      k2 += __shfl_xor(k2, off, 64);
      v2 += __shfl_xor(v2, off, 64);
      aj += __shfl_xor(aj, off, 64);
      bj += __shfl_xor(bj, off, 64);
    }
    int gbase = lane & 48;
    float q0 = __shfl(acc[0][j], gbase, 64);
    float k0 = __shfl(acc[4][j], gbase, 64);
    float v0 = __shfl(acc[8][j], gbase, 64);
    float invq = 1.f / sqrtf(fmaxf(fabsf(q2 - 2.f * q0 * q0), 1e-8f));
    float invk = 1.f / sqrtf(fmaxf(fabsf(k2 - 2.f * k0 * k0), 1e-8f));
    float invv = 1.f / sqrtf(fmaxf(fabsf(v2 - 2.f * v0 * v0), 1e-8f));
    int node = n0w + kg * 4 + j; if (node >= n_nodes) node = n_nodes - 1;
    if (col == 0) { a[node] = aj * invq; b[node] = bj * invk; }
#pragma unroll
    for (int t = 0; t < 4; ++t)
      v[(size_t)node * 64 + t * 16 + col] = acc[t + 8][j] * invv;
  }
}

__global__ void k_deg(const int* __restrict__ ei, int* __restrict__ deg, int n_edges) {
  int e = blockIdx.x * blockDim.x + threadIdx.x;
  if (e < n_edges) atomicAdd(deg + ei[e], 1);
}

// ---- 3-phase block scan: deg -> rowptr (exclusive) ----
__global__ __launch_bounds__(1024) void k_scan1(const int* __restrict__ deg,
                                                int* __restrict__ bsum, int n) {
  __shared__ int ws[16];
  int i = blockIdx.x * 1024 + threadIdx.x;
  int x = (i < n) ? deg[i] : 0;
  int s = x;
#pragma unroll
  for (int off = 1; off < 64; off <<= 1) s += __shfl_xor(s, off, 64);
  if ((threadIdx.x & 63) == 0) ws[threadIdx.x >> 6] = s;
  __syncthreads();
  if (threadIdx.x == 0) {
    int t = 0;
#pragma unroll
    for (int k = 0; k < 16; ++k) t += ws[k];
    bsum[blockIdx.x] = t;
  }
}

__global__ void k_scan2(int* __restrict__ bsum, int nb) {  // 1 wave, nb<=64
  int lane = threadIdx.x;
  int orig = (lane < nb) ? bsum[lane] : 0;
  int x = orig;
#pragma unroll
  for (int off = 1; off < 64; off <<= 1) {
    int y = __shfl_up(x, off, 64);
    if (lane >= off) x += y;
  }
  if (lane < nb) bsum[lane] = x - orig;  // exclusive
}

__global__ __launch_bounds__(1024) void k_scan3(const int* __restrict__ deg,
                                                const int* __restrict__ bsum,
                                                int* __restrict__ rowptr, int n) {
  __shared__ int ws[16];
  __shared__ int woff[16];
  int i = blockIdx.x * 1024 + threadIdx.x;
  int lane = threadIdx.x & 63, w = threadIdx.x >> 6;
  int x = (i < n) ? deg[i] : 0;
  int inc = x;
#pragma unroll
  for (int off = 1; off < 64; off <<= 1) {
    int y = __shfl_up(inc, off, 64);
    if (lane >= off) inc += y;
  }
  if (lane == 63) ws[w] = inc;
  __syncthreads();
  if (threadIdx.x == 0) {
    int t = 0;
#pragma unroll
    for (int k = 0; k < 16; ++k) { woff[k] = t; t += ws[k]; }
  }
  __syncthreads();
  int excl = inc - x + woff[w] + bsum[blockIdx.x];
  if (i < n) rowptr[i] = excl;
  if (i == n - 1) rowptr[n] = excl + x;
}

// score + CSR scatter fused; packed 8B records
__global__ void k_csr(const int* __restrict__ ei, const float* __restrict__ a,
                      const float* __restrict__ b, const int* __restrict__ rowptr,
                      int* __restrict__ cursor, EdgeRec* __restrict__ csr, int n_edges) {
  int e = blockIdx.x * blockDim.x + threadIdx.x;
  if (e >= n_edges) return;
  int src = ei[e];
  int dst = ei[n_edges + e];
  float s = a[src] + b[dst];
  float sc = s > 0.f ? s : 0.01f * s;   // LeakyReLU(0.01)
  int slot = atomicAdd(cursor + src, 1);
  EdgeRec er; er.d = dst; er.s = sc;
  csr[rowptr[src] + slot] = er;
}

// Wave per node: coalesced csr prefetch -> unrolled independent v gathers.
// Writes om[n][64] = to_manifold(origin + softmax-agg of v).
__global__ __launch_bounds__(256) void k_agg1(
    const int* __restrict__ rowptr, const EdgeRec* __restrict__ csr,
    const float* __restrict__ v, float* __restrict__ om, int n_nodes) {
  int wib = threadIdx.x >> 6;
  int lane = threadIdx.x & 63;
  int n = blockIdx.x * 4 + wib;
  if (n >= n_nodes) return;            // wave-uniform

  int r0 = rowptr[n], r1 = rowptr[n + 1];
  int g = lane >> 4, l16 = lane & 15;
  float4 acc = make_float4(0.f, 0.f, 0.f, 0.f);
  float ssl = 0.f;                     // per-lane exp sum

  for (int base = r0; base < r1; base += 64) {
    int cnt = r1 - base; if (cnt > 64) cnt = 64;
    int erd = 0; float wl = 0.f;
    if (lane < cnt) {
      EdgeRec er = csr[base + lane];   // one coalesced 512B load
      erd = er.d;
      wl = __expf(er.s);
    }
    ssl += wl;
#pragma unroll
    for (int j = 0; j < 16; ++j) {
      int idx = g + 4 * j;             // uniform within 16-lane group
      int d = __shfl(erd, idx, 64);
      float w = __shfl(wl, idx, 64);
      if (idx < cnt) {
        float4 vv = ((const float4*)(v + (size_t)d * 64))[l16];
        acc.x = fmaf(w, vv.x, acc.x);
        acc.y = fmaf(w, vv.y, acc.y);
        acc.z = fmaf(w, vv.z, acc.z);
        acc.w = fmaf(w, vv.w, acc.w);
      }
    }
  }

  // reduce 4 groups + exp-sum across wave
#pragma unroll
  for (int off = 16; off < 64; off <<= 1) {
    acc.x += __shfl_xor(acc.x, off, 64);
    acc.y += __shfl_xor(acc.y, off, 64);
    acc.z += __shfl_xor(acc.z, off, 64);
    acc.w += __shfl_xor(acc.w, off, 64);
  }
#pragma unroll
  for (int off = 1; off < 64; off <<= 1) ssl += __shfl_xor(ssl, off, 64);

  if (r1 > r0) {
    float is = 1.f / ssl;
    acc.x *= is; acc.y *= is; acc.z *= is; acc.w *= is;
  }
  if (l16 == 0) acc.x += 1.0f;         // origin (dim 0)

  float s2 = acc.x * acc.x + acc.y * acc.y + acc.z * acc.z + acc.w * acc.w;
#pragma unroll
  for (int off = 1; off < 16; off <<= 1) s2 += __shfl_xor(s2, off, 64);
  float o0 = __shfl(acc.x, 0, 64);
  float inner = s2 - 2.f * o0 * o0;
  float sc = 1.f / sqrtf(fmaxf(fabsf(inner), 1e-8f));
  if (g == 0)
    ((float4*)(om + (size_t)n * 64))[l16] =
        make_float4(acc.x * sc, acc.y * sc, acc.z * sc, acc.w * sc);
}

// MFMA projection with LDS-staged Wproj (hi+lo = 32KB, staged once).
// Block = 256 thr (4 waves), 64 nodes. p = om@Wp^T, x=norm(p), z=norm(x+xH).
__global__ __launch_bounds__(256) void k_proj_mfma(
    const float* __restrict__ om, const u16* __restrict__ Whi,
    const u16* __restrict__ Wlo, const float* __restrict__ xH,
    float* __restrict__ out, int n_nodes) {
  __shared__ __align__(16) u16 WS[2 * 128 * 64];   // 32 KB: [0..8191]=hi, [8192..]=lo
  int tid = threadIdx.x;
  int w = tid >> 6;
  int lane = tid & 63;
  int col = lane & 15;
  int kg = lane >> 4;
  int n0w = blockIdx.x * 64 + w * 16;
  int arow = n0w + col; if (arow >= n_nodes) arow = n_nodes - 1;

  const float* orow = om + (size_t)arow * 64;

  bf16x8 ah[2], al[2];
#pragma unroll
  for (int ks = 0; ks < 2; ++ks) {
    int ko = ks * 32 + kg * 8;
    packhl(*(const float4*)(orow + ko), *(const float4*)(orow + ko + 4), &ah[ks], &al[ks]);
  }

  // stage hi (16KB = chunks 0..15) then lo (chunks 16..31); wave w does c=i*4+w
#pragma unroll
  for (int i = 0; i < 8; ++i) {
    int c = i * 4 + w;
    const u16* src = (c < 16) ? (Whi + c * 512) : (Wlo + (c - 16) * 512);
    uint4 d = *(const uint4*)(src + lane * 8);
    *(uint4*)(WS + c * 512 + lane * 8) = d;
  }
  __syncthreads();

  f32x4 acc[8];
#pragma unroll
  for (int t = 0; t < 8; ++t) acc[t] = (f32x4){0.f, 0.f, 0.f, 0.f};

#pragma unroll
  for (int ks = 0; ks < 2; ++ks) {
#pragma unroll
    for (int t = 0; t < 8; ++t) {
      int off = (16 * t + col) * 64 + ks * 32 + kg * 8;
      bf16x8 bh = *(const bf16x8*)(WS + off);
      bf16x8 bl = *(const bf16x8*)(WS + 8192 + off);
      acc[t] = __builtin_amdgcn_mfma_f32_16x16x32_bf16(ah[ks], bh, acc[t], 0, 0, 0);
      acc[t] = __builtin_amdgcn_mfma_f32_16x16x32_bf16(al[ks], bh, acc[t], 0, 0, 0);
      acc[t] = __builtin_amdgcn_mfma_f32_16x16x32_bf16(ah[ks], bl, acc[t], 0, 0, 0);
    }
  }

  int gbase = lane & 48;
#pragma unroll
  for (int j = 0; j < 4; ++j) {
    int node = n0w + kg * 4 + j; if (node >= n_nodes) node = n_nodes - 1;

    float s2p = 0.f;
#pragma unroll
    for (int t = 0; t < 8; ++t) s2p = fmaf(acc[t][j], acc[t][j], s2p);
#pragma unroll
    for (int off = 1; off < 16; off <<= 1) s2p += __shfl_xor(s2p, off, 64);
    float p0 = __shfl(acc[0][j], gbase, 64);
    float invp = 1.f / sqrtf(fmaxf(fabsf(s2p - 2.f * p0 * p0), 1e-8f));

    float z[8];
    float s2z = 0.f;
#pragma unroll
    for (int t = 0; t < 8; ++t) {
      z[t] = fmaf(acc[t][j], invp, xH[(size_t)node * 128 + t * 16 + col]);
      s2z = fmaf(z[t], z[t], s2z);
    }
#pragma unroll
    for (int off = 1; off < 16; off <<= 1) s2z += __shfl_xor(s2z, off, 64);
    float z0 = __shfl(z[0], gbase, 64);
    float invz = 1.f / sqrtf(fmaxf(fabsf(s2z - 2.f * z0 * z0), 1e-8f));

#pragma unroll
    for (int t = 0; t < 8; ++t)
      out[(size_t)node * 128 + t * 16 + col] = z[t] * invz;
  }
}

extern "C" void kernel_launch(void* const* d_in, const int* in_sizes, int n_in,
                              void* d_out, int out_size, void* d_ws, size_t ws_size,
                              hipStream_t stream) {
  const float* xH    = (const float*)d_in[0];
  const float* xS    = (const float*)d_in[1];
  const int*   ei    = (const int*)d_in[2];
  const float* Wq    = (const float*)d_in[3];
  const float* Wk    = (const float*)d_in[4];
  const float* Wv    = (const float*)d_in[5];
  const float* Ws    = (const float*)d_in[6];
  const float* Wproj = (const float*)d_in[7];
  float* out = (float*)d_out;

  int N = in_sizes[0] / 128;
  int E = in_sizes[2] / 2;

  char* ws = (char*)d_ws;
  size_t off = 0;
  auto alloc = [&](size_t bytes) {
    void* p = ws + off;
    off = (off + bytes + 255) & ~(size_t)255;
    return p;
  };
  float*   a      = (float*)alloc((size_t)N * 4);
  float*   b      = (float*)alloc((size_t)N * 4);
  float*   v      = (float*)alloc((size_t)N * 64 * 4);
  float*   om     = (float*)alloc((size_t)N * 64 * 4);
  EdgeRec* csr    = (EdgeRec*)alloc((size_t)E * 8);
  int*     deg    = (int*)alloc((size_t)N * 4);
  int*     cursor = (int*)alloc((size_t)N * 4);
  int*     rowptr = (int*)alloc((size_t)(N + 1) * 4);
  int*     bsum   = (int*)alloc(64 * 4);
  u16*     Whi    = (u16*)alloc((size_t)192 * 128 * 2);
  u16*     Wlo    = (u16*)alloc((size_t)192 * 128 * 2);
  u16*     Wphi   = (u16*)alloc((size_t)128 * 64 * 2);
  u16*     Wplo   = (u16*)alloc((size_t)128 * 64 * 2);

  int nb = (N + 1023) / 1024;   // 49 <= 64

  k_prep<<<(N + 255) / 256, 256, 0, stream>>>(deg, cursor, N, Wq, Wk, Wv, Wproj,
                                              Whi, Wlo, Wphi, Wplo);

  int n_tiles = (N + 63) / 64;
  k_lin_mfma<<<n_tiles, 256, 0, stream>>>(xH, xS, Whi, Wlo, Ws, a, b, v, N);

  k_deg<<<(E + 255) / 256, 256, 0, stream>>>(ei, deg, E);

  k_scan1<<<nb, 1024, 0, stream>>>(deg, bsum, N);
  k_scan2<<<1, 64, 0, stream>>>(bsum, nb);
  k_scan3<<<nb, 1024, 0, stream>>>(deg, bsum, rowptr, N);

  k_csr<<<(E + 255) / 256, 256, 0, stream>>>(ei, a, b, rowptr, cursor, csr, E);

  k_agg1<<<(N + 3) / 4, 256, 0, stream>>>(rowptr, csr, v, om, N);

  k_proj_mfma<<<n_tiles, 256, 0, stream>>>(om, Wphi, Wplo, xH, out, N);
}